// Round 6
// baseline (682.153 us; speedup 1.0000x reference)
//
#include <hip/hip_runtime.h>

#define NN 50000
#define EE 600000
#define HH 128
#define EDD 16
#define BB 256
#define LL 5
#define NN16 (NN * 16)
#define NSHADOW 8
#define GN 782  // (NN+63)/64

typedef float f32x4 __attribute__((ext_vector_type(4)));
typedef _Float16 f16x4 __attribute__((ext_vector_type(4)));
typedef _Float16 f16x8 __attribute__((ext_vector_type(8)));

// ---------------- all weight prep in one kernel ----------------
__global__ __launch_bounds__(256) void wprep_all_k(
    const float* __restrict__ W0, const float* __restrict__ W1, const float* __restrict__ W2,
    _Float16* __restrict__ H0, _Float16* __restrict__ L0,
    _Float16* __restrict__ H1, _Float16* __restrict__ L1,
    _Float16* __restrict__ H2, _Float16* __restrict__ L2,
    const float* __restrict__ eW, const float* __restrict__ eb, const float* __restrict__ nb,
    _Float16* __restrict__ BXh, _Float16* __restrict__ BXl)
{
    int idx = blockIdx.x * 256 + threadIdx.x;
    if (idx < 3 * 81920) {
        int seg = idx / 81920, r = idx - seg * 81920;
        const float* W = (seg == 0) ? W0 : (seg == 1) ? W1 : W2;
        _Float16* Wh = (seg == 0) ? H0 : (seg == 1) ? H1 : H2;
        _Float16* Wl = (seg == 0) ? L0 : (seg == 1) ? L1 : L2;
        int mat = r >> 14;
        int rr = r & 16383;
        int j = rr & 7, lane = (rr >> 3) & 63, ks = (rr >> 9) & 3, ntw = (rr >> 11) & 7;
        int lm = lane & 15, quad = lane >> 4;
        int n = (ntw >> 1) * 32 + (ntw & 1) * 16 + lm;
        int k = ks * 32 + quad * 8 + j;
        float w = W[(mat << 14) + (k << 7) + n];
        _Float16 h = (_Float16)w;
        Wh[r] = h;
        Wl[r] = (_Float16)(w - (float)h);
    } else {
        int i2 = idx - 3 * 81920;
        if (i2 >= 5 * 8192) return;
        int j = i2 & 7, lane = (i2 >> 3) & 63, ks = (i2 >> 9) & 1, ntw = (i2 >> 10) & 7, l = i2 >> 13;
        int lm = lane & 15, quad = lane >> 4;
        int n = (ntw >> 1) * 32 + (ntw & 1) * 16 + lm;
        int k = ks * 32 + quad * 8 + j;
        float v = 0.f;
        if (k < 16) v = eW[((size_t)l * 16 + k) * 128 + n];
        else if (k < 32) v = eW[((size_t)l * 16 + (k - 16)) * 128 + n];
        else if (k == 32) v = eb[l * 128 + n] + nb[l * 128 + n];
        _Float16 h = (_Float16)v;
        BXh[i2] = h;
        BXl[i2] = (_Float16)(v - (float)h);
    }
}

// ---------------- misc one-time: x->fp16, vn init, vnB zero, pooled8 zero ----------------
__global__ __launch_bounds__(256) void misc_k(const float* __restrict__ x, _Float16* __restrict__ X0,
    const float* __restrict__ vninit, float* __restrict__ vn, _Float16* __restrict__ vnB,
    float* __restrict__ pooled8)
{
    int i = blockIdx.x * 256 + threadIdx.x;
    if (i < NN * 32) {
        float4 v = ((const float4*)x)[i];
        f16x4 o;
        o[0] = (_Float16)v.x; o[1] = (_Float16)v.y; o[2] = (_Float16)v.z; o[3] = (_Float16)v.w;
        ((f16x4*)X0)[i] = o;
    } else {
        int k = i - NN * 32;
        if (k < NSHADOW * BB * HH) pooled8[k] = 0.f;
        if (k < BB * HH) { vn[k] = vninit[k & 127]; vnB[k] = (_Float16)0; }
    }
}

// ---------------- shared GEMM helpers ----------------
__device__ __forceinline__ void mfma_stage16(
    const _Float16* __restrict__ As,
    const _Float16* __restrict__ Wh, const _Float16* __restrict__ Wl,
    int wn, int lm, int quad, int lane, f32x4 acc[4][2])
{
    f16x8 Bh[2][4], Bl[2][4];
#pragma unroll
    for (int nt = 0; nt < 2; ++nt)
#pragma unroll
        for (int ks = 0; ks < 4; ++ks) {
            int fi = ((((wn * 2 + nt) * 4) + ks) * 64 + lane) * 8;
            Bh[nt][ks] = *(const f16x8*)(Wh + fi);
            Bl[nt][ks] = *(const f16x8*)(Wl + fi);
        }
#pragma unroll
    for (int ks = 0; ks < 4; ++ks) {
        f16x8 a[4];
#pragma unroll
        for (int mt = 0; mt < 4; ++mt) {
            int off = (mt * 16 + lm) * 136 + ks * 32 + quad * 8;
            a[mt] = *(const f16x8*)(As + off);
        }
#pragma unroll
        for (int mt = 0; mt < 4; ++mt)
#pragma unroll
            for (int nt = 0; nt < 2; ++nt) {
                acc[mt][nt] = __builtin_amdgcn_mfma_f32_16x16x32_f16(a[mt], Bh[nt][ks], acc[mt][nt], 0, 0, 0);
                acc[mt][nt] = __builtin_amdgcn_mfma_f32_16x16x32_f16(a[mt], Bl[nt][ks], acc[mt][nt], 0, 0, 0);
            }
    }
}

__device__ __forceinline__ void store_f16(const _Float16* __restrict__ Fo,
    _Float16* __restrict__ out, int M, int brow, int tid)
{
    const int r = tid >> 2, cg = tid & 3;
    const int grow = brow + r;
    if (grow >= M) return;
    const f16x8* src = (const f16x8*)(Fo + r * 136 + cg * 32);
    f16x8* dst = (f16x8*)(out + (size_t)grow * 128 + cg * 32);
#pragma unroll
    for (int i = 0; i < 4; ++i) dst[i] = src[i];
}

// ---------------- fused layer kernel (single LDS buffer, 17.4 KB -> 8 blocks/CU cap) ----------------
__global__ __launch_bounds__(256) void layer_k(
    const _Float16* __restrict__ Xin,
    const _Float16* __restrict__ Afix,          // padded to GN*64 rows, pad rows zero
    const _Float16* __restrict__ Cfrag, const _Float16* __restrict__ vnB, int usevn,
    const int* __restrict__ rowstart, const int* __restrict__ csrc,
    const _Float16* __restrict__ WNh, const _Float16* __restrict__ WNl,
    const _Float16* __restrict__ BXh, const _Float16* __restrict__ BXl,
    const _Float16* __restrict__ W1h, const _Float16* __restrict__ W1l, const float* __restrict__ b1,
    const _Float16* __restrict__ W2h, const _Float16* __restrict__ W2l, const float* __restrict__ b2,
    _Float16* __restrict__ Xout, float* __restrict__ pooled8,
    const int* __restrict__ batch, int M)
{
    __shared__ __align__(16) _Float16 bufA[64 * 136];
    const int tid = threadIdx.x, brow = blockIdx.x * 64;

    // ---- gather: bufA[node] = fp16( sum_{e: dst=node} Xin[src_e] ), 2 nodes in flight/group ----
    {
        const int wv = tid >> 6, grp = (tid >> 4) & 3, li = tid & 15;
        const f16x8* X8 = (const f16x8*)Xin;
#pragma unroll
        for (int jj = 0; jj < 2; ++jj) {
            int rn0 = wv * 16 + grp * 4 + jj * 2;
            int rn1 = rn0 + 1;
            int n0 = brow + rn0, n1 = brow + rn1;
            int s0 = 0, e0 = 0, s1 = 0, e1 = 0;
            if (n0 < M) { s0 = rowstart[n0]; e0 = rowstart[n0 + 1]; }
            if (n1 < M) { s1 = rowstart[n1]; e1 = rowstart[n1 + 1]; }
            float ax0[8], ax1[8];
#pragma unroll
            for (int k = 0; k < 8; ++k) { ax0[k] = 0.f; ax1[k] = 0.f; }
            int p0 = s0, p1 = s1;
            while (p0 + 4 <= e0 && p1 + 4 <= e1) {
                int a0 = csrc[p0], a1 = csrc[p0 + 1], a2 = csrc[p0 + 2], a3 = csrc[p0 + 3];
                int b0 = csrc[p1], b1v = csrc[p1 + 1], b2v = csrc[p1 + 2], b3 = csrc[p1 + 3];
                f16x8 xa0 = X8[(size_t)a0 * 16 + li];
                f16x8 xa1 = X8[(size_t)a1 * 16 + li];
                f16x8 xa2 = X8[(size_t)a2 * 16 + li];
                f16x8 xa3 = X8[(size_t)a3 * 16 + li];
                f16x8 xb0 = X8[(size_t)b0 * 16 + li];
                f16x8 xb1 = X8[(size_t)b1v * 16 + li];
                f16x8 xb2 = X8[(size_t)b2v * 16 + li];
                f16x8 xb3 = X8[(size_t)b3 * 16 + li];
#pragma unroll
                for (int k = 0; k < 8; ++k) {
                    ax0[k] += ((float)xa0[k] + (float)xa1[k]) + ((float)xa2[k] + (float)xa3[k]);
                    ax1[k] += ((float)xb0[k] + (float)xb1[k]) + ((float)xb2[k] + (float)xb3[k]);
                }
                p0 += 4; p1 += 4;
            }
            for (; p0 + 4 <= e0; p0 += 4) {
                int a0 = csrc[p0], a1 = csrc[p0 + 1], a2 = csrc[p0 + 2], a3 = csrc[p0 + 3];
                f16x8 xa0 = X8[(size_t)a0 * 16 + li];
                f16x8 xa1 = X8[(size_t)a1 * 16 + li];
                f16x8 xa2 = X8[(size_t)a2 * 16 + li];
                f16x8 xa3 = X8[(size_t)a3 * 16 + li];
#pragma unroll
                for (int k = 0; k < 8; ++k)
                    ax0[k] += ((float)xa0[k] + (float)xa1[k]) + ((float)xa2[k] + (float)xa3[k]);
            }
            for (; p1 + 4 <= e1; p1 += 4) {
                int b0 = csrc[p1], b1v = csrc[p1 + 1], b2v = csrc[p1 + 2], b3 = csrc[p1 + 3];
                f16x8 xb0 = X8[(size_t)b0 * 16 + li];
                f16x8 xb1 = X8[(size_t)b1v * 16 + li];
                f16x8 xb2 = X8[(size_t)b2v * 16 + li];
                f16x8 xb3 = X8[(size_t)b3 * 16 + li];
#pragma unroll
                for (int k = 0; k < 8; ++k)
                    ax1[k] += ((float)xb0[k] + (float)xb1[k]) + ((float)xb2[k] + (float)xb3[k]);
            }
            for (; p0 < e0; ++p0) {
                f16x8 x0 = X8[(size_t)csrc[p0] * 16 + li];
#pragma unroll
                for (int k = 0; k < 8; ++k) ax0[k] += (float)x0[k];
            }
            for (; p1 < e1; ++p1) {
                f16x8 x0 = X8[(size_t)csrc[p1] * 16 + li];
#pragma unroll
                for (int k = 0; k < 8; ++k) ax1[k] += (float)x0[k];
            }
            f16x8 o0, o1;
#pragma unroll
            for (int k = 0; k < 8; ++k) { o0[k] = (_Float16)ax0[k]; o1[k] = (_Float16)ax1[k]; }
            *(f16x8*)(bufA + rn0 * 136 + li * 8) = o0;
            *(f16x8*)(bufA + rn1 * 136 + li * 8) = o1;
        }
    }
    __syncthreads();

    const int lane = tid & 63, wn = tid >> 6, lm = lane & 15, quad = lane >> 4;
    const int colb = wn * 32 + lm;

    f32x4 acc[4][2];
#pragma unroll
    for (int mt = 0; mt < 4; ++mt) { acc[mt][0] = (f32x4)(0.f); acc[mt][1] = (f32x4)(0.f); }

    // K=64: [aggE_hi|aggE_lo|deg] @ [eW;eW;eb+nb]  (A-frags direct from padded global Afix)
#pragma unroll
    for (int ksf = 0; ksf < 2; ++ksf) {
        f16x8 Bh[2], Bl[2];
#pragma unroll
        for (int nt = 0; nt < 2; ++nt) {
            int fi = (((wn * 2 + nt) * 2 + ksf) * 64 + lane) * 8;
            Bh[nt] = *(const f16x8*)(BXh + fi);
            Bl[nt] = *(const f16x8*)(BXl + fi);
        }
#pragma unroll
        for (int mt = 0; mt < 4; ++mt) {
            f16x8 a = *(const f16x8*)(Afix + (size_t)(brow + mt * 16 + lm) * 64 + ksf * 32 + quad * 8);
#pragma unroll
            for (int nt = 0; nt < 2; ++nt) {
                acc[mt][nt] = __builtin_amdgcn_mfma_f32_16x16x32_f16(a, Bh[nt], acc[mt][nt], 0, 0, 0);
                acc[mt][nt] = __builtin_amdgcn_mfma_f32_16x16x32_f16(a, Bl[nt], acc[mt][nt], 0, 0, 0);
            }
        }
    }

    // K=256: C @ vn
    if (usevn) {
        const _Float16* Cb = Cfrag + (size_t)blockIdx.x * 16384;
#pragma unroll
        for (int ks = 0; ks < 8; ++ks) {
            f16x8 bv[2];
#pragma unroll
            for (int nt = 0; nt < 2; ++nt)
                bv[nt] = *(const f16x8*)(vnB + (((ks * 8 + (wn * 2 + nt)) * 64 + lane) * 8));
#pragma unroll
            for (int mt = 0; mt < 4; ++mt) {
                f16x8 av = *(const f16x8*)(Cb + (((mt * 8 + ks) * 64 + lane) * 8));
                acc[mt][0] = __builtin_amdgcn_mfma_f32_16x16x32_f16(av, bv[0], acc[mt][0], 0, 0, 0);
                acc[mt][1] = __builtin_amdgcn_mfma_f32_16x16x32_f16(av, bv[1], acc[mt][1], 0, 0, 0);
            }
        }
    }

    // K=128: AggX @ nW
    mfma_stage16(bufA, WNh, WNl, wn, lm, quad, lane, acc);
    __syncthreads();

    // epilogue 1 -> bufA (single-buffer: sync above ensures all reads done)
#pragma unroll
    for (int mt = 0; mt < 4; ++mt) {
#pragma unroll
        for (int r = 0; r < 4; ++r) {
            int trow = mt * 16 + quad * 4 + r;
            bufA[trow * 136 + colb]      = (_Float16)acc[mt][0][r];
            bufA[trow * 136 + colb + 16] = (_Float16)acc[mt][1][r];
        }
    }
    __syncthreads();

#pragma unroll
    for (int mt = 0; mt < 4; ++mt) { acc[mt][0] = (f32x4)(0.f); acc[mt][1] = (f32x4)(0.f); }
    mfma_stage16(bufA, W1h, W1l, wn, lm, quad, lane, acc);
    __syncthreads();
    {
        const float c0 = b1[colb], c1 = b1[colb + 16];
#pragma unroll
        for (int mt = 0; mt < 4; ++mt) {
#pragma unroll
            for (int r = 0; r < 4; ++r) {
                int trow = mt * 16 + quad * 4 + r;
                bufA[trow * 136 + colb]      = (_Float16)fmaxf(acc[mt][0][r] + c0, 0.f);
                bufA[trow * 136 + colb + 16] = (_Float16)fmaxf(acc[mt][1][r] + c1, 0.f);
            }
        }
    }
    __syncthreads();

#pragma unroll
    for (int mt = 0; mt < 4; ++mt) { acc[mt][0] = (f32x4)(0.f); acc[mt][1] = (f32x4)(0.f); }
    mfma_stage16(bufA, W2h, W2l, wn, lm, quad, lane, acc);
    __syncthreads();
    {
        const float d0 = b2[colb], d1 = b2[colb + 16];
#pragma unroll
        for (int mt = 0; mt < 4; ++mt) {
#pragma unroll
            for (int r = 0; r < 4; ++r) {
                int trow = mt * 16 + quad * 4 + r;
                bufA[trow * 136 + colb]      = (_Float16)fmaxf(acc[mt][0][r] + d0, 0.f);
                bufA[trow * 136 + colb + 16] = (_Float16)fmaxf(acc[mt][1][r] + d1, 0.f);
            }
        }
    }
    __syncthreads();
    store_f16(bufA, Xout, M, brow, tid);

    // pooled partial sums into shadow copy (blockIdx&7)
    {
        float* pooled = pooled8 + (size_t)(blockIdx.x & (NSHADOW - 1)) * (BB * HH);
        const int c = tid & 127, half = tid >> 7;
        const int row0 = half * 32;
        float sum = 0.f;
        int curg = -1;
        for (int r2 = 0; r2 < 32; ++r2) {
            int grow = brow + row0 + r2;
            if (grow >= M) break;
            int g = batch[grow];
            if (g != curg) {
                if (curg >= 0) atomicAdd(&pooled[curg * 128 + c], sum);
                curg = g; sum = 0.f;
            }
            sum += (float)bufA[(row0 + r2) * 136 + c];
        }
        if (curg >= 0) atomicAdd(&pooled[curg * 128 + c], sum);
    }
}

// ---------------- aggE + Afix merged: per-node eattr sum -> [hi|lo|deg|0] fp16 ----------------
__global__ __launch_bounds__(256) void aggfix_k(
    const float* __restrict__ eattr, const int* __restrict__ rowstart,
    const int* __restrict__ cedge, _Float16* __restrict__ Afix, int n)
{
    const int lane = threadIdx.x & 15;
    const int node = blockIdx.x * 16 + (threadIdx.x >> 4);
    if (node >= n) return;
    const int s = rowstart[node], e = rowstart[node + 1];
    float acc = 0.f;
    for (int p = s; p < e; ++p)
        acc += eattr[(size_t)cedge[p] * 16 + lane];
    _Float16 hi = (_Float16)acc;
    _Float16 lo = (_Float16)(acc - (float)hi);
    _Float16* A = Afix + (size_t)node * 64;
    A[lane] = hi;
    A[16 + lane] = lo;
    A[32 + lane] = (lane == 0) ? (_Float16)(float)(e - s) : (_Float16)0;
    A[48 + lane] = (_Float16)0;
}

// ---------------- histogram (deg) + packed u16 Cfrag counts via u32 atomics ----------------
__global__ void histboth_k(const int* __restrict__ dstv, const int* __restrict__ srcv,
                           const int* __restrict__ batch,
                           int* __restrict__ degp, unsigned int* __restrict__ Cpack)
{
    int i = blockIdx.x * 256 + threadIdx.x;
    if (i >= EE) return;
    int d = dstv[i];
    atomicAdd(&degp[(blockIdx.x & 3) * NN16 + (d << 4)], 1);
    int g = batch[srcv[i]];
    int blk = d >> 6, rib = d & 63, mt = rib >> 4, lm = rib & 15;
    int ks = g >> 5, quad = (g >> 3) & 3, j = g & 7;
    size_t e = (size_t)blk * 16384 + (size_t)(((mt * 8 + ks) * 64) + quad * 16 + lm) * 8 + j;
    atomicAdd(&Cpack[e >> 1], 1u << ((e & 1) * 16));
}

// ---------------- in-place convert packed u16 counts -> fp16 ----------------
__global__ __launch_bounds__(256) void ccvt_k(unsigned int* __restrict__ Cpack)
{
    int i = blockIdx.x * 256 + threadIdx.x;
    if (i >= GN * 16384 / 2) return;
    unsigned int v = Cpack[i];
    _Float16 lo = (_Float16)(float)(v & 0xffffu);
    _Float16 hi = (_Float16)(float)(v >> 16);
    unsigned short lu = __builtin_bit_cast(unsigned short, lo);
    unsigned short hu = __builtin_bit_cast(unsigned short, hi);
    Cpack[i] = (unsigned int)lu | ((unsigned int)hu << 16);
}

// ---------------- VN update (writes frag-ordered vnB) ----------------
__global__ __launch_bounds__(128) void vn_update_k(
    float* __restrict__ pooled8, const int* __restrict__ gstart,
    const float* __restrict__ W0, const float* __restrict__ b0,
    const float* __restrict__ W1, const float* __restrict__ b1,
    float* __restrict__ vn, _Float16* __restrict__ vnB)
{
    __shared__ float p[128], q[128];
    const int g = blockIdx.x, t = threadIdx.x;
    float cnt = (float)(gstart[g + 1] - gstart[g]);
    if (cnt < 1.f) cnt = 1.f;
    float sum = 0.f;
#pragma unroll
    for (int s = 0; s < NSHADOW; ++s) {
        float* slot = pooled8 + (size_t)s * (BB * HH) + g * 128 + t;
        sum += *slot;
        *slot = 0.f;
    }
    p[t] = sum / cnt;
    __syncthreads();
    float a0 = b0[t];
    for (int k = 0; k < 128; ++k) a0 = fmaf(p[k], W0[k * 128 + t], a0);
    q[t] = fmaxf(a0, 0.f);
    __syncthreads();
    float a1 = b1[t];
    for (int k = 0; k < 128; ++k) a1 = fmaf(q[k], W1[k * 128 + t], a1);
    float nv = vn[g * 128 + t] + fmaxf(a1, 0.f);
    vn[g * 128 + t] = nv;
    {
        int ks = g >> 5, quad = (g >> 3) & 3, j = g & 7;
        int tt = ((t >> 5) << 1) | ((t >> 4) & 1);
        int lanev = quad * 16 + (t & 15);
        vnB[((ks * 8 + tt) * 64 + lanev) * 8 + j] = (_Float16)nv;
    }
}

// ---------------- final classifier ----------------
__global__ __launch_bounds__(128) void fc_k(
    const float* __restrict__ pooled8, const int* __restrict__ gstart,
    const float* __restrict__ W, const float* __restrict__ b,
    float* __restrict__ out)
{
    __shared__ float p[128];
    const int g = blockIdx.x, t = threadIdx.x;
    float cnt = (float)(gstart[g + 1] - gstart[g]);
    if (cnt < 1.f) cnt = 1.f;
    float sum = 0.f;
#pragma unroll
    for (int s = 0; s < NSHADOW; ++s)
        sum += pooled8[(size_t)s * (BB * HH) + g * 128 + t];
    p[t] = sum / cnt;
    __syncthreads();
    float acc = b[t];
    for (int k = 0; k < 128; ++k) acc = fmaf(p[k], W[k * 128 + t], acc);
    out[g * 128 + t] = acc;
}

// ---------------- CSR build ----------------
__global__ void scan_deg_k(const int* __restrict__ degp, int n, int* __restrict__ out, int* __restrict__ bsum)
{
    __shared__ int s[256];
    int gid = blockIdx.x * 256 + threadIdx.x;
    int v = 0;
    if (gid < n) {
        int o = gid << 4;
        v = degp[o] + degp[NN16 + o] + degp[2 * NN16 + o] + degp[3 * NN16 + o];
    }
    s[threadIdx.x] = v;
    __syncthreads();
    for (int off = 1; off < 256; off <<= 1) {
        int t = (threadIdx.x >= off) ? s[threadIdx.x - off] : 0;
        __syncthreads();
        s[threadIdx.x] += t;
        __syncthreads();
    }
    int incl = s[threadIdx.x];
    if (gid < n) out[gid] = incl - v;
    if (bsum != nullptr && threadIdx.x == 255) bsum[blockIdx.x] = incl;
}

__global__ void scan_k(const int* __restrict__ in, int n, int* __restrict__ out,
                       const int* __restrict__ batch, int* __restrict__ gstart)
{
    __shared__ int s[256];
    int v = (threadIdx.x < n) ? in[threadIdx.x] : 0;
    s[threadIdx.x] = v;
    __syncthreads();
    for (int off = 1; off < 256; off <<= 1) {
        int t = (threadIdx.x >= off) ? s[threadIdx.x - off] : 0;
        __syncthreads();
        s[threadIdx.x] += t;
        __syncthreads();
    }
    if (threadIdx.x < n) out[threadIdx.x] = s[threadIdx.x] - v;
    {
        int b = threadIdx.x;
        int lo = 0, hi = NN;
        while (lo < hi) {
            int mid = (lo + hi) >> 1;
            if (batch[mid] < b) lo = mid + 1; else hi = mid;
        }
        gstart[b] = lo;
        if (threadIdx.x == 0) gstart[BB] = NN;
    }
}

__global__ void addoff_k(int* __restrict__ data, const int* __restrict__ boff,
                         int* __restrict__ cursorp, int n, int total)
{
    int i = blockIdx.x * 256 + threadIdx.x;
    if (i < n) {
        int v = data[i] + boff[blockIdx.x];
        data[i] = v;
        cursorp[i << 4] = v;
    }
    if (i == 0) data[n] = total;
}

__global__ void fill_k(const int* __restrict__ dst, const int* __restrict__ src, int n,
                       int* __restrict__ cursorp, int* __restrict__ csrc, int* __restrict__ cedge)
{
    int e = blockIdx.x * 256 + threadIdx.x;
    if (e < n) {
        int slot = atomicAdd(&cursorp[dst[e] << 4], 1);
        csrc[slot] = src[e];
        cedge[slot] = e;
    }
}

// ---------------- Launch ----------------
extern "C" void kernel_launch(void* const* d_in, const int* in_sizes, int n_in,
                              void* d_out, int out_size, void* d_ws, size_t ws_size,
                              hipStream_t stream)
{
    (void)in_sizes; (void)n_in; (void)out_size; (void)ws_size;
    const float* x       = (const float*)d_in[0];
    const float* eattr   = (const float*)d_in[1];
    const float* node_W  = (const float*)d_in[2];
    const float* node_b  = (const float*)d_in[3];
    const float* edge_W  = (const float*)d_in[4];
    const float* edge_b  = (const float*)d_in[5];
    const float* mlp1_W  = (const float*)d_in[6];
    const float* mlp1_b  = (const float*)d_in[7];
    const float* mlp2_W  = (const float*)d_in[8];
    const float* mlp2_b  = (const float*)d_in[9];
    const float* vn_w0   = (const float*)d_in[10];
    const float* vn_b0   = (const float*)d_in[11];
    const float* vn_w1   = (const float*)d_in[12];
    const float* vn_b1   = (const float*)d_in[13];
    const float* fc_W    = (const float*)d_in[14];
    const float* fc_b    = (const float*)d_in[15];
    const float* vn_init = (const float*)d_in[16];
    const int*   eidx    = (const int*)d_in[17];
    const int*   batch   = (const int*)d_in[18];
    const int* srcv = eidx;
    const int* dstv = eidx + EE;

    char* wp = (char*)d_ws;
    auto alloc = [&](size_t bytes) -> void* {
        void* p = (void*)wp;
        wp += (bytes + 255) & ~(size_t)255;
        return p;
    };
    // zero-init region: degp | Cfrag | Afix (padded) contiguous -> one memset
    int* degp       = (int*)alloc((size_t)4 * NN16 * 4);               // 12.8 MB
    _Float16* Cfrag = (_Float16*)alloc((size_t)GN * 16384 * 2);        // 25.6 MB
    _Float16* Afix  = (_Float16*)alloc((size_t)GN * 64 * 64 * 2);      // 6.4 MB (padded to GN*64 rows)
    const size_t zero_bytes = (size_t)4 * NN16 * 4 + (size_t)GN * 16384 * 2 + (size_t)GN * 64 * 64 * 2;

    _Float16* X0   = (_Float16*)alloc((size_t)NN * HH * 2);
    _Float16* X1   = (_Float16*)alloc((size_t)NN * HH * 2);
    _Float16* X2   = (_Float16*)alloc((size_t)NN * HH * 2);
    float* vn      = (float*)alloc((size_t)BB * HH * 4);
    _Float16* vnB  = (_Float16*)alloc((size_t)BB * HH * 2);
    float* pooled8 = (float*)alloc((size_t)NSHADOW * BB * HH * 4);
    int* rowstart  = (int*)alloc((size_t)(NN + 1) * 4);
    int* cursorp   = (int*)alloc((size_t)NN16 * 4);
    int* csrc      = (int*)alloc((size_t)EE * 4);
    int* cedge     = (int*)alloc((size_t)EE * 4);
    int* bsum      = (int*)alloc(256 * 4);
    int* boff      = (int*)alloc(256 * 4);
    int* gstart    = (int*)alloc((size_t)(BB + 1) * 4);
    _Float16* WtN_h = (_Float16*)alloc((size_t)5 * 16384 * 2);
    _Float16* WtN_l = (_Float16*)alloc((size_t)5 * 16384 * 2);
    _Float16* Wt1_h = (_Float16*)alloc((size_t)5 * 16384 * 2);
    _Float16* Wt1_l = (_Float16*)alloc((size_t)5 * 16384 * 2);
    _Float16* Wt2_h = (_Float16*)alloc((size_t)5 * 16384 * 2);
    _Float16* Wt2_l = (_Float16*)alloc((size_t)5 * 16384 * 2);
    _Float16* BXh   = (_Float16*)alloc((size_t)5 * 8192 * 2);
    _Float16* BXl   = (_Float16*)alloc((size_t)5 * 8192 * 2);

    (void)hipMemsetAsync(degp, 0, zero_bytes, stream);

    histboth_k<<<(EE + 255) / 256, 256, 0, stream>>>(dstv, srcv, batch, degp, (unsigned int*)Cfrag);

    const int NB1 = (NN + 255) / 256;
    scan_deg_k<<<NB1, 256, 0, stream>>>(degp, NN, rowstart, bsum);
    scan_k<<<1, 256, 0, stream>>>(bsum, NB1, boff, batch, gstart);
    addoff_k<<<NB1, 256, 0, stream>>>(rowstart, boff, cursorp, NN, EE);
    fill_k<<<(EE + 255) / 256, 256, 0, stream>>>(dstv, srcv, EE, cursorp, csrc, cedge);
    aggfix_k<<<(NN + 15) / 16, 256, 0, stream>>>(eattr, rowstart, cedge, Afix, NN);
    ccvt_k<<<(GN * 16384 / 2 + 255) / 256, 256, 0, stream>>>((unsigned int*)Cfrag);

    misc_k<<<(NN * 32 + NSHADOW * BB * HH) / 256, 256, 0, stream>>>(x, X0, vn_init, vn, vnB, pooled8);
    wprep_all_k<<<(3 * 81920 + 5 * 8192) / 256, 256, 0, stream>>>(
        node_W, mlp1_W, mlp2_W, WtN_h, WtN_l, Wt1_h, Wt1_l, Wt2_h, Wt2_l,
        edge_W, edge_b, node_b, BXh, BXl);

    const _Float16* xin = X0;
    for (int l = 0; l < LL; ++l) {
        _Float16* xout = (l & 1) ? X2 : X1;
        layer_k<<<GN, 256, 0, stream>>>(xin, Afix, Cfrag, vnB, (l > 0) ? 1 : 0,
            rowstart, csrc,
            WtN_h + (size_t)l * 16384, WtN_l + (size_t)l * 16384,
            BXh + (size_t)l * 8192, BXl + (size_t)l * 8192,
            Wt1_h + (size_t)l * 16384, Wt1_l + (size_t)l * 16384, mlp1_b + (size_t)l * HH,
            Wt2_h + (size_t)l * 16384, Wt2_l + (size_t)l * 16384, mlp2_b + (size_t)l * HH,
            xout, pooled8, batch, NN);
        if (l < LL - 1)
            vn_update_k<<<BB, 128, 0, stream>>>(pooled8, gstart, vn_w0, vn_b0, vn_w1, vn_b1, vn, vnB);
        xin = xout;
    }
    fc_k<<<BB, 128, 0, stream>>>(pooled8, gstart, fc_W, fc_b, (float*)d_out);
}

// Round 7
// 655.437 us; speedup vs baseline: 1.0408x; 1.0408x over previous
//
#include <hip/hip_runtime.h>

#define NN 50000
#define EE 600000
#define HH 128
#define EDD 16
#define BB 256
#define LL 5
#define NN16 (NN * 16)
#define NSHADOW 8
#define GN 782  // (NN+63)/64

typedef float f32x4 __attribute__((ext_vector_type(4)));
typedef _Float16 f16x4 __attribute__((ext_vector_type(4)));
typedef _Float16 f16x8 __attribute__((ext_vector_type(8)));

// ---------------- all weight prep in one kernel ----------------
__global__ __launch_bounds__(256) void wprep_all_k(
    const float* __restrict__ W0, const float* __restrict__ W1, const float* __restrict__ W2,
    _Float16* __restrict__ H0, _Float16* __restrict__ L0,
    _Float16* __restrict__ H1, _Float16* __restrict__ L1,
    _Float16* __restrict__ H2, _Float16* __restrict__ L2,
    const float* __restrict__ eW, const float* __restrict__ eb, const float* __restrict__ nb,
    _Float16* __restrict__ BXh, _Float16* __restrict__ BXl)
{
    int idx = blockIdx.x * 256 + threadIdx.x;
    if (idx < 3 * 81920) {
        int seg = idx / 81920, r = idx - seg * 81920;
        const float* W = (seg == 0) ? W0 : (seg == 1) ? W1 : W2;
        _Float16* Wh = (seg == 0) ? H0 : (seg == 1) ? H1 : H2;
        _Float16* Wl = (seg == 0) ? L0 : (seg == 1) ? L1 : L2;
        int mat = r >> 14;
        int rr = r & 16383;
        int j = rr & 7, lane = (rr >> 3) & 63, ks = (rr >> 9) & 3, ntw = (rr >> 11) & 7;
        int lm = lane & 15, quad = lane >> 4;
        int n = (ntw >> 1) * 32 + (ntw & 1) * 16 + lm;
        int k = ks * 32 + quad * 8 + j;
        float w = W[(mat << 14) + (k << 7) + n];
        _Float16 h = (_Float16)w;
        Wh[r] = h;
        Wl[r] = (_Float16)(w - (float)h);
    } else {
        int i2 = idx - 3 * 81920;
        if (i2 >= 5 * 8192) return;
        int j = i2 & 7, lane = (i2 >> 3) & 63, ks = (i2 >> 9) & 1, ntw = (i2 >> 10) & 7, l = i2 >> 13;
        int lm = lane & 15, quad = lane >> 4;
        int n = (ntw >> 1) * 32 + (ntw & 1) * 16 + lm;
        int k = ks * 32 + quad * 8 + j;
        float v = 0.f;
        if (k < 16) v = eW[((size_t)l * 16 + k) * 128 + n];
        else if (k < 32) v = eW[((size_t)l * 16 + (k - 16)) * 128 + n];
        else if (k == 32) v = eb[l * 128 + n] + nb[l * 128 + n];
        _Float16 h = (_Float16)v;
        BXh[i2] = h;
        BXl[i2] = (_Float16)(v - (float)h);
    }
}

// ---------------- misc one-time: x->fp16, vn init, vn16 zero, pooled8 zero ----------------
__global__ __launch_bounds__(256) void misc_k(const float* __restrict__ x, _Float16* __restrict__ X0,
    const float* __restrict__ vninit, float* __restrict__ vn, _Float16* __restrict__ vn16,
    float* __restrict__ pooled8)
{
    int i = blockIdx.x * 256 + threadIdx.x;
    if (i < NN * 32) {
        float4 v = ((const float4*)x)[i];
        f16x4 o;
        o[0] = (_Float16)v.x; o[1] = (_Float16)v.y; o[2] = (_Float16)v.z; o[3] = (_Float16)v.w;
        ((f16x4*)X0)[i] = o;
    } else {
        int k = i - NN * 32;
        if (k < NSHADOW * BB * HH) pooled8[k] = 0.f;
        if (k < BB * HH) { vn[k] = vninit[k & 127]; vn16[k] = (_Float16)0; }
    }
}

// ---------------- shared GEMM helpers ----------------
__device__ __forceinline__ void mfma_stage16(
    const _Float16* __restrict__ As,
    const _Float16* __restrict__ Wh, const _Float16* __restrict__ Wl,
    int wn, int lm, int quad, int lane, f32x4 acc[4][2])
{
    f16x8 Bh[2][4], Bl[2][4];
#pragma unroll
    for (int nt = 0; nt < 2; ++nt)
#pragma unroll
        for (int ks = 0; ks < 4; ++ks) {
            int fi = ((((wn * 2 + nt) * 4) + ks) * 64 + lane) * 8;
            Bh[nt][ks] = *(const f16x8*)(Wh + fi);
            Bl[nt][ks] = *(const f16x8*)(Wl + fi);
        }
#pragma unroll
    for (int ks = 0; ks < 4; ++ks) {
        f16x8 a[4];
#pragma unroll
        for (int mt = 0; mt < 4; ++mt) {
            int off = (mt * 16 + lm) * 136 + ks * 32 + quad * 8;
            a[mt] = *(const f16x8*)(As + off);
        }
#pragma unroll
        for (int mt = 0; mt < 4; ++mt)
#pragma unroll
            for (int nt = 0; nt < 2; ++nt) {
                acc[mt][nt] = __builtin_amdgcn_mfma_f32_16x16x32_f16(a[mt], Bh[nt][ks], acc[mt][nt], 0, 0, 0);
                acc[mt][nt] = __builtin_amdgcn_mfma_f32_16x16x32_f16(a[mt], Bl[nt][ks], acc[mt][nt], 0, 0, 0);
            }
    }
}

__device__ __forceinline__ void store_f16(const _Float16* __restrict__ Fo,
    _Float16* __restrict__ out, int M, int brow, int tid)
{
    const int r = tid >> 2, cg = tid & 3;
    const int grow = brow + r;
    if (grow >= M) return;
    const f16x8* src = (const f16x8*)(Fo + r * 136 + cg * 32);
    f16x8* dst = (f16x8*)(out + (size_t)grow * 128 + cg * 32);
#pragma unroll
    for (int i = 0; i < 4; ++i) dst[i] = src[i];
}

// ---------------- fused layer kernel (r4 structure; VnSum gathered from L2-hot vn16 table) ----------------
__global__ __launch_bounds__(256) void layer_k(
    const _Float16* __restrict__ Xin,
    const _Float16* __restrict__ Afix,          // padded to GN*64 rows, pad rows zero
    const _Float16* __restrict__ vn16, int usevn,
    const int* __restrict__ rowstart, const unsigned int* __restrict__ csrc,  // src | (g<<16)
    const _Float16* __restrict__ WNh, const _Float16* __restrict__ WNl,
    const _Float16* __restrict__ BXh, const _Float16* __restrict__ BXl,
    const _Float16* __restrict__ W1h, const _Float16* __restrict__ W1l, const float* __restrict__ b1,
    const _Float16* __restrict__ W2h, const _Float16* __restrict__ W2l, const float* __restrict__ b2,
    _Float16* __restrict__ Xout, float* __restrict__ pooled8,
    const int* __restrict__ batch, int M)
{
    __shared__ __align__(16) _Float16 bufA[64 * 136];   // X gather-sum, then MLP ping-pong
    __shared__ __align__(16) _Float16 bufB[64 * 136];   // VnSum, then MLP ping-pong
    const int tid = threadIdx.x, brow = blockIdx.x * 64;

    // gather phase: bufA[node] = fp16( sum X[src] ); bufB[node] = fp16( sum vn16[g_src] )
    {
        const int wv = tid >> 6, grp = (tid >> 4) & 3, li = tid & 15;
        const f16x8* X8 = (const f16x8*)Xin;
        const f16x8* V8 = (const f16x8*)vn16;
        for (int j = 0; j < 4; ++j) {
            int rnode = wv * 16 + grp * 4 + j;
            int node = brow + rnode;
            f16x8 o = (f16x8)(_Float16)0;
            f16x8 ov = (f16x8)(_Float16)0;
            if (node < M) {
                int s = rowstart[node], e = rowstart[node + 1];
                float ax[8], ev[8];
#pragma unroll
                for (int k = 0; k < 8; ++k) { ax[k] = 0.f; ev[k] = 0.f; }
                int p = s;
                for (; p + 4 <= e; p += 4) {
                    unsigned c0 = csrc[p], c1 = csrc[p + 1], c2 = csrc[p + 2], c3 = csrc[p + 3];
                    f16x8 x0 = X8[(size_t)(c0 & 0xffffu) * 16 + li];
                    f16x8 x1 = X8[(size_t)(c1 & 0xffffu) * 16 + li];
                    f16x8 x2 = X8[(size_t)(c2 & 0xffffu) * 16 + li];
                    f16x8 x3 = X8[(size_t)(c3 & 0xffffu) * 16 + li];
#pragma unroll
                    for (int k = 0; k < 8; ++k)
                        ax[k] += ((float)x0[k] + (float)x1[k]) + ((float)x2[k] + (float)x3[k]);
                    if (usevn) {
                        f16x8 v0 = V8[(c0 >> 16) * 16 + li];
                        f16x8 v1 = V8[(c1 >> 16) * 16 + li];
                        f16x8 v2 = V8[(c2 >> 16) * 16 + li];
                        f16x8 v3 = V8[(c3 >> 16) * 16 + li];
#pragma unroll
                        for (int k = 0; k < 8; ++k)
                            ev[k] += ((float)v0[k] + (float)v1[k]) + ((float)v2[k] + (float)v3[k]);
                    }
                }
                for (; p < e; ++p) {
                    unsigned c0 = csrc[p];
                    f16x8 x0 = X8[(size_t)(c0 & 0xffffu) * 16 + li];
#pragma unroll
                    for (int k = 0; k < 8; ++k) ax[k] += (float)x0[k];
                    if (usevn) {
                        f16x8 v0 = V8[(c0 >> 16) * 16 + li];
#pragma unroll
                        for (int k = 0; k < 8; ++k) ev[k] += (float)v0[k];
                    }
                }
#pragma unroll
                for (int k = 0; k < 8; ++k) { o[k] = (_Float16)ax[k]; ov[k] = (_Float16)ev[k]; }
            }
            *(f16x8*)(bufA + rnode * 136 + li * 8) = o;
            *(f16x8*)(bufB + rnode * 136 + li * 8) = ov;
        }
    }
    __syncthreads();

    const int lane = tid & 63, wn = tid >> 6, lm = lane & 15, quad = lane >> 4;
    const int colb = wn * 32 + lm;

    f32x4 acc[4][2];
#pragma unroll
    for (int mt = 0; mt < 4; ++mt) { acc[mt][0] = (f32x4)(0.f); acc[mt][1] = (f32x4)(0.f); }

    // K=64: [aggE_hi|aggE_lo|deg] @ [eW;eW;eb+nb]  (A-frags direct from padded global Afix)
#pragma unroll
    for (int ksf = 0; ksf < 2; ++ksf) {
        f16x8 Bh[2], Bl[2];
#pragma unroll
        for (int nt = 0; nt < 2; ++nt) {
            int fi = (((wn * 2 + nt) * 2 + ksf) * 64 + lane) * 8;
            Bh[nt] = *(const f16x8*)(BXh + fi);
            Bl[nt] = *(const f16x8*)(BXl + fi);
        }
#pragma unroll
        for (int mt = 0; mt < 4; ++mt) {
            f16x8 a = *(const f16x8*)(Afix + (size_t)(brow + mt * 16 + lm) * 64 + ksf * 32 + quad * 8);
#pragma unroll
            for (int nt = 0; nt < 2; ++nt) {
                acc[mt][nt] = __builtin_amdgcn_mfma_f32_16x16x32_f16(a, Bh[nt], acc[mt][nt], 0, 0, 0);
                acc[mt][nt] = __builtin_amdgcn_mfma_f32_16x16x32_f16(a, Bl[nt], acc[mt][nt], 0, 0, 0);
            }
        }
    }

    // K=128: AggX @ nW
    mfma_stage16(bufA, WNh, WNl, wn, lm, quad, lane, acc);
    __syncthreads();

    // epilogue 1: agg = acc + VnSum -> bufA
#pragma unroll
    for (int mt = 0; mt < 4; ++mt) {
#pragma unroll
        for (int r = 0; r < 4; ++r) {
            int trow = mt * 16 + quad * 4 + r;
            bufA[trow * 136 + colb]      = (_Float16)(acc[mt][0][r] + (float)bufB[trow * 136 + colb]);
            bufA[trow * 136 + colb + 16] = (_Float16)(acc[mt][1][r] + (float)bufB[trow * 136 + colb + 16]);
        }
    }
    __syncthreads();

#pragma unroll
    for (int mt = 0; mt < 4; ++mt) { acc[mt][0] = (f32x4)(0.f); acc[mt][1] = (f32x4)(0.f); }
    mfma_stage16(bufA, W1h, W1l, wn, lm, quad, lane, acc);
    {
        const float c0 = b1[colb], c1 = b1[colb + 16];
#pragma unroll
        for (int mt = 0; mt < 4; ++mt) {
#pragma unroll
            for (int r = 0; r < 4; ++r) {
                int trow = mt * 16 + quad * 4 + r;
                bufB[trow * 136 + colb]      = (_Float16)fmaxf(acc[mt][0][r] + c0, 0.f);
                bufB[trow * 136 + colb + 16] = (_Float16)fmaxf(acc[mt][1][r] + c1, 0.f);
            }
        }
    }
    __syncthreads();

#pragma unroll
    for (int mt = 0; mt < 4; ++mt) { acc[mt][0] = (f32x4)(0.f); acc[mt][1] = (f32x4)(0.f); }
    mfma_stage16(bufB, W2h, W2l, wn, lm, quad, lane, acc);
    {
        const float d0 = b2[colb], d1 = b2[colb + 16];
#pragma unroll
        for (int mt = 0; mt < 4; ++mt) {
#pragma unroll
            for (int r = 0; r < 4; ++r) {
                int trow = mt * 16 + quad * 4 + r;
                bufA[trow * 136 + colb]      = (_Float16)fmaxf(acc[mt][0][r] + d0, 0.f);
                bufA[trow * 136 + colb + 16] = (_Float16)fmaxf(acc[mt][1][r] + d1, 0.f);
            }
        }
    }
    __syncthreads();
    store_f16(bufA, Xout, M, brow, tid);

    // pooled partial sums into shadow copy (blockIdx&7)
    {
        float* pooled = pooled8 + (size_t)(blockIdx.x & (NSHADOW - 1)) * (BB * HH);
        const int c = tid & 127, half = tid >> 7;
        const int row0 = half * 32;
        float sum = 0.f;
        int curg = -1;
        for (int r2 = 0; r2 < 32; ++r2) {
            int grow = brow + row0 + r2;
            if (grow >= M) break;
            int g = batch[grow];
            if (g != curg) {
                if (curg >= 0) atomicAdd(&pooled[curg * 128 + c], sum);
                curg = g; sum = 0.f;
            }
            sum += (float)bufA[(row0 + r2) * 136 + c];
        }
        if (curg >= 0) atomicAdd(&pooled[curg * 128 + c], sum);
    }
}

// ---------------- aggE + Afix merged: per-node eattr sum -> [hi|lo|deg|0] fp16 ----------------
__global__ __launch_bounds__(256) void aggfix_k(
    const float* __restrict__ eattr, const int* __restrict__ rowstart,
    const int* __restrict__ cedge, _Float16* __restrict__ Afix, int n)
{
    const int lane = threadIdx.x & 15;
    const int node = blockIdx.x * 16 + (threadIdx.x >> 4);
    if (node >= n) return;
    const int s = rowstart[node], e = rowstart[node + 1];
    float acc = 0.f;
    for (int p = s; p < e; ++p)
        acc += eattr[(size_t)cedge[p] * 16 + lane];
    _Float16 hi = (_Float16)acc;
    _Float16 lo = (_Float16)(acc - (float)hi);
    _Float16* A = Afix + (size_t)node * 64;
    A[lane] = hi;
    A[16 + lane] = lo;
    A[32 + lane] = (lane == 0) ? (_Float16)(float)(e - s) : (_Float16)0;
    A[48 + lane] = (_Float16)0;
}

// ---------------- degree histogram (4 shadows) ----------------
__global__ void histp_k(const int* __restrict__ idx, int n, int* __restrict__ cntp)
{
    int i = blockIdx.x * 256 + threadIdx.x;
    if (i < n) atomicAdd(&cntp[(blockIdx.x & 3) * NN16 + (idx[i] << 4)], 1);
}

// ---------------- VN update (writes linear fp16 vn16 table) ----------------
__global__ __launch_bounds__(128) void vn_update_k(
    float* __restrict__ pooled8, const int* __restrict__ gstart,
    const float* __restrict__ W0, const float* __restrict__ b0,
    const float* __restrict__ W1, const float* __restrict__ b1,
    float* __restrict__ vn, _Float16* __restrict__ vn16)
{
    __shared__ float p[128], q[128];
    const int g = blockIdx.x, t = threadIdx.x;
    float cnt = (float)(gstart[g + 1] - gstart[g]);
    if (cnt < 1.f) cnt = 1.f;
    float sum = 0.f;
#pragma unroll
    for (int s = 0; s < NSHADOW; ++s) {
        float* slot = pooled8 + (size_t)s * (BB * HH) + g * 128 + t;
        sum += *slot;
        *slot = 0.f;
    }
    p[t] = sum / cnt;
    __syncthreads();
    float a0 = b0[t];
    for (int k = 0; k < 128; ++k) a0 = fmaf(p[k], W0[k * 128 + t], a0);
    q[t] = fmaxf(a0, 0.f);
    __syncthreads();
    float a1 = b1[t];
    for (int k = 0; k < 128; ++k) a1 = fmaf(q[k], W1[k * 128 + t], a1);
    float nv = vn[g * 128 + t] + fmaxf(a1, 0.f);
    vn[g * 128 + t] = nv;
    vn16[g * 128 + t] = (_Float16)nv;
}

// ---------------- final classifier ----------------
__global__ __launch_bounds__(128) void fc_k(
    const float* __restrict__ pooled8, const int* __restrict__ gstart,
    const float* __restrict__ W, const float* __restrict__ b,
    float* __restrict__ out)
{
    __shared__ float p[128];
    const int g = blockIdx.x, t = threadIdx.x;
    float cnt = (float)(gstart[g + 1] - gstart[g]);
    if (cnt < 1.f) cnt = 1.f;
    float sum = 0.f;
#pragma unroll
    for (int s = 0; s < NSHADOW; ++s)
        sum += pooled8[(size_t)s * (BB * HH) + g * 128 + t];
    p[t] = sum / cnt;
    __syncthreads();
    float acc = b[t];
    for (int k = 0; k < 128; ++k) acc = fmaf(p[k], W[k * 128 + t], acc);
    out[g * 128 + t] = acc;
}

// ---------------- CSR build ----------------
__global__ void scan_deg_k(const int* __restrict__ degp, int n, int* __restrict__ out, int* __restrict__ bsum)
{
    __shared__ int s[256];
    int gid = blockIdx.x * 256 + threadIdx.x;
    int v = 0;
    if (gid < n) {
        int o = gid << 4;
        v = degp[o] + degp[NN16 + o] + degp[2 * NN16 + o] + degp[3 * NN16 + o];
    }
    s[threadIdx.x] = v;
    __syncthreads();
    for (int off = 1; off < 256; off <<= 1) {
        int t = (threadIdx.x >= off) ? s[threadIdx.x - off] : 0;
        __syncthreads();
        s[threadIdx.x] += t;
        __syncthreads();
    }
    int incl = s[threadIdx.x];
    if (gid < n) out[gid] = incl - v;
    if (bsum != nullptr && threadIdx.x == 255) bsum[blockIdx.x] = incl;
}

__global__ void scan_k(const int* __restrict__ in, int n, int* __restrict__ out,
                       const int* __restrict__ batch, int* __restrict__ gstart)
{
    __shared__ int s[256];
    int v = (threadIdx.x < n) ? in[threadIdx.x] : 0;
    s[threadIdx.x] = v;
    __syncthreads();
    for (int off = 1; off < 256; off <<= 1) {
        int t = (threadIdx.x >= off) ? s[threadIdx.x - off] : 0;
        __syncthreads();
        s[threadIdx.x] += t;
        __syncthreads();
    }
    if (threadIdx.x < n) out[threadIdx.x] = s[threadIdx.x] - v;
    {
        int b = threadIdx.x;
        int lo = 0, hi = NN;
        while (lo < hi) {
            int mid = (lo + hi) >> 1;
            if (batch[mid] < b) lo = mid + 1; else hi = mid;
        }
        gstart[b] = lo;
        if (threadIdx.x == 0) gstart[BB] = NN;
    }
}

__global__ void addoff_k(int* __restrict__ data, const int* __restrict__ boff,
                         int* __restrict__ cursorp, int n, int total)
{
    int i = blockIdx.x * 256 + threadIdx.x;
    if (i < n) {
        int v = data[i] + boff[blockIdx.x];
        data[i] = v;
        cursorp[i << 4] = v;
    }
    if (i == 0) data[n] = total;
}

// fill: pack src (16b) | graph-of-src (8b) into csrc; edge id into cedge
__global__ void fill_k(const int* __restrict__ dst, const int* __restrict__ src, int n,
                       const int* __restrict__ batch,
                       int* __restrict__ cursorp, unsigned int* __restrict__ csrc,
                       int* __restrict__ cedge)
{
    int e = blockIdx.x * 256 + threadIdx.x;
    if (e < n) {
        int sv = src[e];
        unsigned g = (unsigned)batch[sv];
        int slot = atomicAdd(&cursorp[dst[e] << 4], 1);
        csrc[slot] = (unsigned)sv | (g << 16);
        cedge[slot] = e;
    }
}

// ---------------- Launch ----------------
extern "C" void kernel_launch(void* const* d_in, const int* in_sizes, int n_in,
                              void* d_out, int out_size, void* d_ws, size_t ws_size,
                              hipStream_t stream)
{
    (void)in_sizes; (void)n_in; (void)out_size; (void)ws_size;
    const float* x       = (const float*)d_in[0];
    const float* eattr   = (const float*)d_in[1];
    const float* node_W  = (const float*)d_in[2];
    const float* node_b  = (const float*)d_in[3];
    const float* edge_W  = (const float*)d_in[4];
    const float* edge_b  = (const float*)d_in[5];
    const float* mlp1_W  = (const float*)d_in[6];
    const float* mlp1_b  = (const float*)d_in[7];
    const float* mlp2_W  = (const float*)d_in[8];
    const float* mlp2_b  = (const float*)d_in[9];
    const float* vn_w0   = (const float*)d_in[10];
    const float* vn_b0   = (const float*)d_in[11];
    const float* vn_w1   = (const float*)d_in[12];
    const float* vn_b1   = (const float*)d_in[13];
    const float* fc_W    = (const float*)d_in[14];
    const float* fc_b    = (const float*)d_in[15];
    const float* vn_init = (const float*)d_in[16];
    const int*   eidx    = (const int*)d_in[17];
    const int*   batch   = (const int*)d_in[18];
    const int* srcv = eidx;
    const int* dstv = eidx + EE;

    char* wp = (char*)d_ws;
    auto alloc = [&](size_t bytes) -> void* {
        void* p = (void*)wp;
        wp += (bytes + 255) & ~(size_t)255;
        return p;
    };
    // zero-init region: degp | Afix (padded) contiguous -> one memset (19.2 MB)
    int* degp       = (int*)alloc((size_t)4 * NN16 * 4);               // 12.8 MB
    _Float16* Afix  = (_Float16*)alloc((size_t)GN * 64 * 64 * 2);      // 6.4 MB
    const size_t zero_bytes = (size_t)4 * NN16 * 4 + (size_t)GN * 64 * 64 * 2;

    _Float16* X0   = (_Float16*)alloc((size_t)NN * HH * 2);
    _Float16* X1   = (_Float16*)alloc((size_t)NN * HH * 2);
    _Float16* X2   = (_Float16*)alloc((size_t)NN * HH * 2);
    float* vn      = (float*)alloc((size_t)BB * HH * 4);
    _Float16* vn16 = (_Float16*)alloc((size_t)BB * HH * 2);
    float* pooled8 = (float*)alloc((size_t)NSHADOW * BB * HH * 4);
    int* rowstart  = (int*)alloc((size_t)(NN + 1) * 4);
    int* cursorp   = (int*)alloc((size_t)NN16 * 4);
    unsigned int* csrc = (unsigned int*)alloc((size_t)EE * 4);
    int* cedge     = (int*)alloc((size_t)EE * 4);
    int* bsum      = (int*)alloc(256 * 4);
    int* boff      = (int*)alloc(256 * 4);
    int* gstart    = (int*)alloc((size_t)(BB + 1) * 4);
    _Float16* WtN_h = (_Float16*)alloc((size_t)5 * 16384 * 2);
    _Float16* WtN_l = (_Float16*)alloc((size_t)5 * 16384 * 2);
    _Float16* Wt1_h = (_Float16*)alloc((size_t)5 * 16384 * 2);
    _Float16* Wt1_l = (_Float16*)alloc((size_t)5 * 16384 * 2);
    _Float16* Wt2_h = (_Float16*)alloc((size_t)5 * 16384 * 2);
    _Float16* Wt2_l = (_Float16*)alloc((size_t)5 * 16384 * 2);
    _Float16* BXh   = (_Float16*)alloc((size_t)5 * 8192 * 2);
    _Float16* BXl   = (_Float16*)alloc((size_t)5 * 8192 * 2);

    (void)hipMemsetAsync(degp, 0, zero_bytes, stream);

    histp_k<<<(EE + 255) / 256, 256, 0, stream>>>(dstv, EE, degp);

    const int NB1 = (NN + 255) / 256;
    scan_deg_k<<<NB1, 256, 0, stream>>>(degp, NN, rowstart, bsum);
    scan_k<<<1, 256, 0, stream>>>(bsum, NB1, boff, batch, gstart);
    addoff_k<<<NB1, 256, 0, stream>>>(rowstart, boff, cursorp, NN, EE);
    fill_k<<<(EE + 255) / 256, 256, 0, stream>>>(dstv, srcv, EE, batch, cursorp, csrc, cedge);
    aggfix_k<<<(NN + 15) / 16, 256, 0, stream>>>(eattr, rowstart, cedge, Afix, NN);

    misc_k<<<(NN * 32 + NSHADOW * BB * HH) / 256, 256, 0, stream>>>(x, X0, vn_init, vn, vn16, pooled8);
    wprep_all_k<<<(3 * 81920 + 5 * 8192) / 256, 256, 0, stream>>>(
        node_W, mlp1_W, mlp2_W, WtN_h, WtN_l, Wt1_h, Wt1_l, Wt2_h, Wt2_l,
        edge_W, edge_b, node_b, BXh, BXl);

    const _Float16* xin = X0;
    for (int l = 0; l < LL; ++l) {
        _Float16* xout = (l & 1) ? X2 : X1;
        layer_k<<<GN, 256, 0, stream>>>(xin, Afix, vn16, (l > 0) ? 1 : 0,
            rowstart, csrc,
            WtN_h + (size_t)l * 16384, WtN_l + (size_t)l * 16384,
            BXh + (size_t)l * 8192, BXl + (size_t)l * 8192,
            Wt1_h + (size_t)l * 16384, Wt1_l + (size_t)l * 16384, mlp1_b + (size_t)l * HH,
            Wt2_h + (size_t)l * 16384, Wt2_l + (size_t)l * 16384, mlp2_b + (size_t)l * HH,
            xout, pooled8, batch, NN);
        if (l < LL - 1)
            vn_update_k<<<BB, 128, 0, stream>>>(pooled8, gstart, vn_w0, vn_b0, vn_w1, vn_b1, vn, vn16);
        xin = xout;
    }
    fc_k<<<BB, 128, 0, stream>>>(pooled8, gstart, fc_W, fc_b, (float*)d_out);
}

// Round 8
// 588.948 us; speedup vs baseline: 1.1583x; 1.1129x over previous
//
#include <hip/hip_runtime.h>

#define NN 50000
#define EE 600000
#define HH 128
#define EDD 16
#define BB 256
#define LL 5
#define NN16 (NN * 16)
#define NSHADOW 8
#define GN 782  // (NN+63)/64

typedef float f32x4 __attribute__((ext_vector_type(4)));
typedef _Float16 f16x4 __attribute__((ext_vector_type(4)));
typedef _Float16 f16x8 __attribute__((ext_vector_type(8)));

// ---------------- all weight prep in one kernel ----------------
__global__ __launch_bounds__(256) void wprep_all_k(
    const float* __restrict__ W0, const float* __restrict__ W1, const float* __restrict__ W2,
    _Float16* __restrict__ H0, _Float16* __restrict__ L0,
    _Float16* __restrict__ H1, _Float16* __restrict__ L1,
    _Float16* __restrict__ H2, _Float16* __restrict__ L2,
    const float* __restrict__ eW, const float* __restrict__ eb, const float* __restrict__ nb,
    _Float16* __restrict__ BXh, _Float16* __restrict__ BXl)
{
    int idx = blockIdx.x * 256 + threadIdx.x;
    if (idx < 3 * 81920) {
        int seg = idx / 81920, r = idx - seg * 81920;
        const float* W = (seg == 0) ? W0 : (seg == 1) ? W1 : W2;
        _Float16* Wh = (seg == 0) ? H0 : (seg == 1) ? H1 : H2;
        _Float16* Wl = (seg == 0) ? L0 : (seg == 1) ? L1 : L2;
        int mat = r >> 14;
        int rr = r & 16383;
        int j = rr & 7, lane = (rr >> 3) & 63, ks = (rr >> 9) & 3, ntw = (rr >> 11) & 7;
        int lm = lane & 15, quad = lane >> 4;
        int n = (ntw >> 1) * 32 + (ntw & 1) * 16 + lm;
        int k = ks * 32 + quad * 8 + j;
        float w = W[(mat << 14) + (k << 7) + n];
        _Float16 h = (_Float16)w;
        Wh[r] = h;
        Wl[r] = (_Float16)(w - (float)h);
    } else {
        int i2 = idx - 3 * 81920;
        if (i2 >= 5 * 8192) return;
        int j = i2 & 7, lane = (i2 >> 3) & 63, ks = (i2 >> 9) & 1, ntw = (i2 >> 10) & 7, l = i2 >> 13;
        int lm = lane & 15, quad = lane >> 4;
        int n = (ntw >> 1) * 32 + (ntw & 1) * 16 + lm;
        int k = ks * 32 + quad * 8 + j;
        float v = 0.f;
        if (k < 16) v = eW[((size_t)l * 16 + k) * 128 + n];
        else if (k < 32) v = eW[((size_t)l * 16 + (k - 16)) * 128 + n];
        else if (k == 32) v = eb[l * 128 + n] + nb[l * 128 + n];
        _Float16 h = (_Float16)v;
        BXh[i2] = h;
        BXl[i2] = (_Float16)(v - (float)h);
    }
}

// ---------------- misc one-time: x->fp16, vn init, vnB zero, pooled8 zero ----------------
__global__ __launch_bounds__(256) void misc_k(const float* __restrict__ x, _Float16* __restrict__ X0,
    const float* __restrict__ vninit, float* __restrict__ vn, _Float16* __restrict__ vnB,
    float* __restrict__ pooled8)
{
    int i = blockIdx.x * 256 + threadIdx.x;
    if (i < NN * 32) {
        float4 v = ((const float4*)x)[i];
        f16x4 o;
        o[0] = (_Float16)v.x; o[1] = (_Float16)v.y; o[2] = (_Float16)v.z; o[3] = (_Float16)v.w;
        ((f16x4*)X0)[i] = o;
    } else {
        int k = i - NN * 32;
        if (k < NSHADOW * BB * HH) pooled8[k] = 0.f;
        if (k < BB * HH) { vn[k] = vninit[k & 127]; vnB[k] = (_Float16)0; }
    }
}

// ---------------- 8-wave GEMM helper: each wave owns one 16-col tile (ntw = wn) ----------------
__device__ __forceinline__ void mfma_stage8w(
    const _Float16* __restrict__ As,
    const _Float16* __restrict__ Wh, const _Float16* __restrict__ Wl,
    int wn, int lm, int quad, int lane, f32x4 acc[4])
{
    f16x8 Bh[4], Bl[4];
#pragma unroll
    for (int ks = 0; ks < 4; ++ks) {
        int fi = ((wn * 4 + ks) * 64 + lane) * 8;
        Bh[ks] = *(const f16x8*)(Wh + fi);
        Bl[ks] = *(const f16x8*)(Wl + fi);
    }
#pragma unroll
    for (int ks = 0; ks < 4; ++ks) {
        f16x8 a[4];
#pragma unroll
        for (int mt = 0; mt < 4; ++mt) {
            int off = (mt * 16 + lm) * 136 + ks * 32 + quad * 8;
            a[mt] = *(const f16x8*)(As + off);
        }
#pragma unroll
        for (int mt = 0; mt < 4; ++mt) {
            acc[mt] = __builtin_amdgcn_mfma_f32_16x16x32_f16(a[mt], Bh[ks], acc[mt], 0, 0, 0);
            acc[mt] = __builtin_amdgcn_mfma_f32_16x16x32_f16(a[mt], Bl[ks], acc[mt], 0, 0, 0);
        }
    }
}

// ---------------- fused layer kernel: r4 body at 512 threads (8 waves) ----------------
__global__ __launch_bounds__(512, 6) void layer_k(
    const _Float16* __restrict__ Xin,
    const _Float16* __restrict__ Afix,
    const _Float16* __restrict__ Cfrag, const _Float16* __restrict__ vnB, int usevn,
    const int* __restrict__ rowstart, const int2* __restrict__ csr,
    const _Float16* __restrict__ WNh, const _Float16* __restrict__ WNl,
    const _Float16* __restrict__ BXh, const _Float16* __restrict__ BXl,
    const _Float16* __restrict__ W1h, const _Float16* __restrict__ W1l, const float* __restrict__ b1,
    const _Float16* __restrict__ W2h, const _Float16* __restrict__ W2l, const float* __restrict__ b2,
    _Float16* __restrict__ Xout, float* __restrict__ pooled8,
    const int* __restrict__ batch, int M)
{
    __shared__ __align__(16) _Float16 bufA[64 * 136];
    __shared__ __align__(16) _Float16 bufB[64 * 136];   // first 64*72 doubles as Afix stage
    const int tid = threadIdx.x, brow = blockIdx.x * 64;

    // stage Afix [64 x 64] fp16 at stride 72 into bufB (512 threads: 8B each)
    {
        const int r = tid >> 3, cg = tid & 7;
        const int grow = brow + r;
        _Float16* p = bufB + r * 72 + cg * 8;
        if (grow < M) {
            *(f16x8*)p = *(const f16x8*)(Afix + (size_t)grow * 64 + cg * 8);
        } else {
            *(f16x8*)p = (f16x8)(_Float16)0;
        }
    }

    // gather phase: 32 groups x 2 rows each (same inner loop as r4)
    {
        const int gid = tid >> 4, li = tid & 15;
        const f16x8* X8 = (const f16x8*)Xin;
#pragma unroll
        for (int j = 0; j < 2; ++j) {
            int rnode = gid * 2 + j;
            int node = brow + rnode;
            f16x8 o = (f16x8)(_Float16)0;
            if (node < M) {
                int s = rowstart[node], e = rowstart[node + 1];
                float ax[8];
#pragma unroll
                for (int k = 0; k < 8; ++k) ax[k] = 0.f;
                int p = s;
                for (; p + 4 <= e; p += 4) {
                    int s0 = csr[p].x, s1 = csr[p + 1].x, s2 = csr[p + 2].x, s3 = csr[p + 3].x;
                    f16x8 x0 = X8[(size_t)s0 * 16 + li];
                    f16x8 x1 = X8[(size_t)s1 * 16 + li];
                    f16x8 x2 = X8[(size_t)s2 * 16 + li];
                    f16x8 x3 = X8[(size_t)s3 * 16 + li];
#pragma unroll
                    for (int k = 0; k < 8; ++k)
                        ax[k] += ((float)x0[k] + (float)x1[k]) + ((float)x2[k] + (float)x3[k]);
                }
                for (; p < e; ++p) {
                    f16x8 x0 = X8[(size_t)csr[p].x * 16 + li];
#pragma unroll
                    for (int k = 0; k < 8; ++k) ax[k] += (float)x0[k];
                }
#pragma unroll
                for (int k = 0; k < 8; ++k) o[k] = (_Float16)ax[k];
            }
            *(f16x8*)(bufA + rnode * 136 + li * 8) = o;
        }
    }
    __syncthreads();

    const int lane = tid & 63, wn = tid >> 6, lm = lane & 15, quad = lane >> 4;
    const int colb = (wn >> 1) * 32 + (wn & 1) * 16 + lm;

    f32x4 acc[4];
#pragma unroll
    for (int mt = 0; mt < 4; ++mt) acc[mt] = (f32x4)(0.f);

    // K=64: [aggE_hi|aggE_lo|deg] @ [eW;eW;eb+nb]  (ntw = wn)
#pragma unroll
    for (int ksf = 0; ksf < 2; ++ksf) {
        int fi = ((wn * 2 + ksf) * 64 + lane) * 8;
        f16x8 Bh = *(const f16x8*)(BXh + fi);
        f16x8 Bl = *(const f16x8*)(BXl + fi);
#pragma unroll
        for (int mt = 0; mt < 4; ++mt) {
            f16x8 a = *(const f16x8*)(bufB + (mt * 16 + lm) * 72 + ksf * 32 + quad * 8);
            acc[mt] = __builtin_amdgcn_mfma_f32_16x16x32_f16(a, Bh, acc[mt], 0, 0, 0);
            acc[mt] = __builtin_amdgcn_mfma_f32_16x16x32_f16(a, Bl, acc[mt], 0, 0, 0);
        }
    }

    // K=256: C @ vn (column tile = wn)
    if (usevn) {
        const _Float16* Cb = Cfrag + (size_t)blockIdx.x * 16384;
#pragma unroll
        for (int ks = 0; ks < 8; ++ks) {
            f16x8 bv = *(const f16x8*)(vnB + (((ks * 8 + wn) * 64 + lane) * 8));
#pragma unroll
            for (int mt = 0; mt < 4; ++mt) {
                f16x8 av = *(const f16x8*)(Cb + (((mt * 8 + ks) * 64 + lane) * 8));
                acc[mt] = __builtin_amdgcn_mfma_f32_16x16x32_f16(av, bv, acc[mt], 0, 0, 0);
            }
        }
    }

    // K=128: AggX @ nW
    mfma_stage8w(bufA, WNh, WNl, wn, lm, quad, lane, acc);
    __syncthreads();

    // epilogue 1 (no relu; bias terms already inside GEMM): agg -> bufA
#pragma unroll
    for (int mt = 0; mt < 4; ++mt) {
#pragma unroll
        for (int r = 0; r < 4; ++r) {
            int trow = mt * 16 + quad * 4 + r;
            bufA[trow * 136 + colb] = (_Float16)acc[mt][r];
        }
    }
    __syncthreads();

#pragma unroll
    for (int mt = 0; mt < 4; ++mt) acc[mt] = (f32x4)(0.f);
    mfma_stage8w(bufA, W1h, W1l, wn, lm, quad, lane, acc);
    {
        const float c0 = b1[colb];
#pragma unroll
        for (int mt = 0; mt < 4; ++mt) {
#pragma unroll
            for (int r = 0; r < 4; ++r) {
                int trow = mt * 16 + quad * 4 + r;
                bufB[trow * 136 + colb] = (_Float16)fmaxf(acc[mt][r] + c0, 0.f);
            }
        }
    }
    __syncthreads();

#pragma unroll
    for (int mt = 0; mt < 4; ++mt) acc[mt] = (f32x4)(0.f);
    mfma_stage8w(bufB, W2h, W2l, wn, lm, quad, lane, acc);
    {
        const float d0 = b2[colb];
#pragma unroll
        for (int mt = 0; mt < 4; ++mt) {
#pragma unroll
            for (int r = 0; r < 4; ++r) {
                int trow = mt * 16 + quad * 4 + r;
                bufA[trow * 136 + colb] = (_Float16)fmaxf(acc[mt][r] + d0, 0.f);
            }
        }
    }
    __syncthreads();

    // store (512 threads: 16 cols each)
    {
        const int r = tid >> 3, cg = tid & 7;
        const int grow = brow + r;
        if (grow < M) {
            const f16x8* src = (const f16x8*)(bufA + r * 136 + cg * 16);
            f16x8* dst = (f16x8*)(Xout + (size_t)grow * 128 + cg * 16);
            dst[0] = src[0];
            dst[1] = src[1];
        }
    }

    // pooled partial sums into shadow copy (blockIdx&7): 4 segments x 16 rows
    {
        float* pooled = pooled8 + (size_t)(blockIdx.x & (NSHADOW - 1)) * (BB * HH);
        const int c = tid & 127, seg = tid >> 7;
        const int row0 = seg * 16;
        float sum = 0.f;
        int curg = -1;
        for (int r2 = 0; r2 < 16; ++r2) {
            int grow = brow + row0 + r2;
            if (grow >= M) break;
            int g = batch[grow];
            if (g != curg) {
                if (curg >= 0) atomicAdd(&pooled[curg * 128 + c], sum);
                curg = g; sum = 0.f;
            }
            sum += (float)bufA[(row0 + r2) * 136 + c];
        }
        if (curg >= 0) atomicAdd(&pooled[curg * 128 + c], sum);
    }
}

// ---------------- aggE + Afix merged: per-node eattr sum -> [hi|lo|deg|0] fp16 ----------------
__global__ __launch_bounds__(256) void aggfix_k(
    const float* __restrict__ eattr, const int* __restrict__ rowstart,
    const int2* __restrict__ csr, _Float16* __restrict__ Afix, int n)
{
    const int lane = threadIdx.x & 15;
    const int node = blockIdx.x * 16 + (threadIdx.x >> 4);
    if (node >= n) return;
    const int s = rowstart[node], e = rowstart[node + 1];
    float acc = 0.f;
    for (int p = s; p < e; ++p)
        acc += eattr[(size_t)csr[p].y * 16 + lane];
    _Float16 hi = (_Float16)acc;
    _Float16 lo = (_Float16)(acc - (float)hi);
    _Float16* A = Afix + (size_t)node * 64;
    A[lane] = hi;
    A[16 + lane] = lo;
    A[32 + lane] = (lane == 0) ? (_Float16)(float)(e - s) : (_Float16)0;
    A[48 + lane] = (_Float16)0;
}

// ---------------- histogram (deg) + packed u16 Cfrag counts via u32 atomics ----------------
__global__ void histboth_k(const int* __restrict__ dstv, const int* __restrict__ srcv,
                           const int* __restrict__ batch,
                           int* __restrict__ degp, unsigned int* __restrict__ Cpack)
{
    int i = blockIdx.x * 256 + threadIdx.x;
    if (i >= EE) return;
    int d = dstv[i];
    atomicAdd(&degp[(blockIdx.x & 3) * NN16 + (d << 4)], 1);
    int g = batch[srcv[i]];
    int blk = d >> 6, rib = d & 63, mt = rib >> 4, lm = rib & 15;
    int ks = g >> 5, quad = (g >> 3) & 3, j = g & 7;
    size_t e = (size_t)blk * 16384 + (size_t)(((mt * 8 + ks) * 64) + quad * 16 + lm) * 8 + j;
    atomicAdd(&Cpack[e >> 1], 1u << ((e & 1) * 16));
}

// ---------------- in-place convert packed u16 counts -> fp16 ----------------
__global__ __launch_bounds__(256) void ccvt_k(unsigned int* __restrict__ Cpack)
{
    int i = blockIdx.x * 256 + threadIdx.x;
    if (i >= GN * 16384 / 2) return;
    unsigned int v = Cpack[i];
    _Float16 lo = (_Float16)(float)(v & 0xffffu);
    _Float16 hi = (_Float16)(float)(v >> 16);
    unsigned short lu = __builtin_bit_cast(unsigned short, lo);
    unsigned short hu = __builtin_bit_cast(unsigned short, hi);
    Cpack[i] = (unsigned int)lu | ((unsigned int)hu << 16);
}

// ---------------- VN update (writes frag-ordered vnB) ----------------
__global__ __launch_bounds__(128) void vn_update_k(
    float* __restrict__ pooled8, const int* __restrict__ gstart,
    const float* __restrict__ W0, const float* __restrict__ b0,
    const float* __restrict__ W1, const float* __restrict__ b1,
    float* __restrict__ vn, _Float16* __restrict__ vnB)
{
    __shared__ float p[128], q[128];
    const int g = blockIdx.x, t = threadIdx.x;
    float cnt = (float)(gstart[g + 1] - gstart[g]);
    if (cnt < 1.f) cnt = 1.f;
    float sum = 0.f;
#pragma unroll
    for (int s = 0; s < NSHADOW; ++s) {
        float* slot = pooled8 + (size_t)s * (BB * HH) + g * 128 + t;
        sum += *slot;
        *slot = 0.f;
    }
    p[t] = sum / cnt;
    __syncthreads();
    float a0 = b0[t];
    for (int k = 0; k < 128; ++k) a0 = fmaf(p[k], W0[k * 128 + t], a0);
    q[t] = fmaxf(a0, 0.f);
    __syncthreads();
    float a1 = b1[t];
    for (int k = 0; k < 128; ++k) a1 = fmaf(q[k], W1[k * 128 + t], a1);
    float nv = vn[g * 128 + t] + fmaxf(a1, 0.f);
    vn[g * 128 + t] = nv;
    {
        int ks = g >> 5, quad = (g >> 3) & 3, j = g & 7;
        int tt = ((t >> 5) << 1) | ((t >> 4) & 1);
        int lanev = quad * 16 + (t & 15);
        vnB[((ks * 8 + tt) * 64 + lanev) * 8 + j] = (_Float16)nv;
    }
}

// ---------------- final classifier ----------------
__global__ __launch_bounds__(128) void fc_k(
    const float* __restrict__ pooled8, const int* __restrict__ gstart,
    const float* __restrict__ W, const float* __restrict__ b,
    float* __restrict__ out)
{
    __shared__ float p[128];
    const int g = blockIdx.x, t = threadIdx.x;
    float cnt = (float)(gstart[g + 1] - gstart[g]);
    if (cnt < 1.f) cnt = 1.f;
    float sum = 0.f;
#pragma unroll
    for (int s = 0; s < NSHADOW; ++s)
        sum += pooled8[(size_t)s * (BB * HH) + g * 128 + t];
    p[t] = sum / cnt;
    __syncthreads();
    float acc = b[t];
    for (int k = 0; k < 128; ++k) acc = fmaf(p[k], W[k * 128 + t], acc);
    out[g * 128 + t] = acc;
}

// ---------------- CSR build ----------------
__global__ void scan_deg_k(const int* __restrict__ degp, int n, int* __restrict__ out, int* __restrict__ bsum)
{
    __shared__ int s[256];
    int gid = blockIdx.x * 256 + threadIdx.x;
    int v = 0;
    if (gid < n) {
        int o = gid << 4;
        v = degp[o] + degp[NN16 + o] + degp[2 * NN16 + o] + degp[3 * NN16 + o];
    }
    s[threadIdx.x] = v;
    __syncthreads();
    for (int off = 1; off < 256; off <<= 1) {
        int t = (threadIdx.x >= off) ? s[threadIdx.x - off] : 0;
        __syncthreads();
        s[threadIdx.x] += t;
        __syncthreads();
    }
    int incl = s[threadIdx.x];
    if (gid < n) out[gid] = incl - v;
    if (bsum != nullptr && threadIdx.x == 255) bsum[blockIdx.x] = incl;
}

__global__ void scan_k(const int* __restrict__ in, int n, int* __restrict__ out,
                       const int* __restrict__ batch, int* __restrict__ gstart)
{
    __shared__ int s[256];
    int v = (threadIdx.x < n) ? in[threadIdx.x] : 0;
    s[threadIdx.x] = v;
    __syncthreads();
    for (int off = 1; off < 256; off <<= 1) {
        int t = (threadIdx.x >= off) ? s[threadIdx.x - off] : 0;
        __syncthreads();
        s[threadIdx.x] += t;
        __syncthreads();
    }
    if (threadIdx.x < n) out[threadIdx.x] = s[threadIdx.x] - v;
    {
        int b = threadIdx.x;
        int lo = 0, hi = NN;
        while (lo < hi) {
            int mid = (lo + hi) >> 1;
            if (batch[mid] < b) lo = mid + 1; else hi = mid;
        }
        gstart[b] = lo;
        if (threadIdx.x == 0) gstart[BB] = NN;
    }
}

__global__ void addoff_k(int* __restrict__ data, const int* __restrict__ boff,
                         int* __restrict__ cursorp, int n, int total)
{
    int i = blockIdx.x * 256 + threadIdx.x;
    if (i < n) {
        int v = data[i] + boff[blockIdx.x];
        data[i] = v;
        cursorp[i << 4] = v;
    }
    if (i == 0) data[n] = total;
}

__global__ void fill_k(const int* __restrict__ dst, const int* __restrict__ src, int n,
                       int* __restrict__ cursorp, int2* __restrict__ csr)
{
    int e = blockIdx.x * 256 + threadIdx.x;
    if (e < n) {
        int slot = atomicAdd(&cursorp[dst[e] << 4], 1);
        int2 pr; pr.x = src[e]; pr.y = e;
        csr[slot] = pr;
    }
}

// ---------------- Launch ----------------
extern "C" void kernel_launch(void* const* d_in, const int* in_sizes, int n_in,
                              void* d_out, int out_size, void* d_ws, size_t ws_size,
                              hipStream_t stream)
{
    (void)in_sizes; (void)n_in; (void)out_size; (void)ws_size;
    const float* x       = (const float*)d_in[0];
    const float* eattr   = (const float*)d_in[1];
    const float* node_W  = (const float*)d_in[2];
    const float* node_b  = (const float*)d_in[3];
    const float* edge_W  = (const float*)d_in[4];
    const float* edge_b  = (const float*)d_in[5];
    const float* mlp1_W  = (const float*)d_in[6];
    const float* mlp1_b  = (const float*)d_in[7];
    const float* mlp2_W  = (const float*)d_in[8];
    const float* mlp2_b  = (const float*)d_in[9];
    const float* vn_w0   = (const float*)d_in[10];
    const float* vn_b0   = (const float*)d_in[11];
    const float* vn_w1   = (const float*)d_in[12];
    const float* vn_b1   = (const float*)d_in[13];
    const float* fc_W    = (const float*)d_in[14];
    const float* fc_b    = (const float*)d_in[15];
    const float* vn_init = (const float*)d_in[16];
    const int*   eidx    = (const int*)d_in[17];
    const int*   batch   = (const int*)d_in[18];
    const int* srcv = eidx;
    const int* dstv = eidx + EE;

    char* wp = (char*)d_ws;
    auto alloc = [&](size_t bytes) -> void* {
        void* p = (void*)wp;
        wp += (bytes + 255) & ~(size_t)255;
        return p;
    };
    // zero-init region: degp | Cfrag contiguous (one memset)
    int* degp       = (int*)alloc((size_t)4 * NN16 * 4);             // 12.8 MB
    _Float16* Cfrag = (_Float16*)alloc((size_t)GN * 16384 * 2);      // 25.6 MB
    const size_t zero_bytes = (size_t)4 * NN16 * 4 + (size_t)GN * 16384 * 2;

    _Float16* X0   = (_Float16*)alloc((size_t)NN * HH * 2);
    _Float16* X1   = (_Float16*)alloc((size_t)NN * HH * 2);
    _Float16* X2   = (_Float16*)alloc((size_t)NN * HH * 2);
    _Float16* Afix = (_Float16*)alloc((size_t)NN * 64 * 2);
    float* vn      = (float*)alloc((size_t)BB * HH * 4);
    _Float16* vnB  = (_Float16*)alloc((size_t)BB * HH * 2);
    float* pooled8 = (float*)alloc((size_t)NSHADOW * BB * HH * 4);
    int* rowstart  = (int*)alloc((size_t)(NN + 1) * 4);
    int* cursorp   = (int*)alloc((size_t)NN16 * 4);
    int2* csr      = (int2*)alloc((size_t)EE * 8);
    int* bsum      = (int*)alloc(256 * 4);
    int* boff      = (int*)alloc(256 * 4);
    int* gstart    = (int*)alloc((size_t)(BB + 1) * 4);
    _Float16* WtN_h = (_Float16*)alloc((size_t)5 * 16384 * 2);
    _Float16* WtN_l = (_Float16*)alloc((size_t)5 * 16384 * 2);
    _Float16* Wt1_h = (_Float16*)alloc((size_t)5 * 16384 * 2);
    _Float16* Wt1_l = (_Float16*)alloc((size_t)5 * 16384 * 2);
    _Float16* Wt2_h = (_Float16*)alloc((size_t)5 * 16384 * 2);
    _Float16* Wt2_l = (_Float16*)alloc((size_t)5 * 16384 * 2);
    _Float16* BXh   = (_Float16*)alloc((size_t)5 * 8192 * 2);
    _Float16* BXl   = (_Float16*)alloc((size_t)5 * 8192 * 2);

    (void)hipMemsetAsync(degp, 0, zero_bytes, stream);

    histboth_k<<<(EE + 255) / 256, 256, 0, stream>>>(dstv, srcv, batch, degp, (unsigned int*)Cfrag);

    const int NB1 = (NN + 255) / 256;
    scan_deg_k<<<NB1, 256, 0, stream>>>(degp, NN, rowstart, bsum);
    scan_k<<<1, 256, 0, stream>>>(bsum, NB1, boff, batch, gstart);
    addoff_k<<<NB1, 256, 0, stream>>>(rowstart, boff, cursorp, NN, EE);
    fill_k<<<(EE + 255) / 256, 256, 0, stream>>>(dstv, srcv, EE, cursorp, csr);
    aggfix_k<<<(NN + 15) / 16, 256, 0, stream>>>(eattr, rowstart, csr, Afix, NN);
    ccvt_k<<<(GN * 16384 / 2 + 255) / 256, 256, 0, stream>>>((unsigned int*)Cfrag);

    misc_k<<<(NN * 32 + NSHADOW * BB * HH) / 256, 256, 0, stream>>>(x, X0, vn_init, vn, vnB, pooled8);
    wprep_all_k<<<(3 * 81920 + 5 * 8192) / 256, 256, 0, stream>>>(
        node_W, mlp1_W, mlp2_W, WtN_h, WtN_l, Wt1_h, Wt1_l, Wt2_h, Wt2_l,
        edge_W, edge_b, node_b, BXh, BXl);

    const _Float16* xin = X0;
    for (int l = 0; l < LL; ++l) {
        _Float16* xout = (l & 1) ? X2 : X1;
        layer_k<<<GN, 512, 0, stream>>>(xin, Afix, Cfrag, vnB, (l > 0) ? 1 : 0,
            rowstart, csr,
            WtN_h + (size_t)l * 16384, WtN_l + (size_t)l * 16384,
            BXh + (size_t)l * 8192, BXl + (size_t)l * 8192,
            Wt1_h + (size_t)l * 16384, Wt1_l + (size_t)l * 16384, mlp1_b + (size_t)l * HH,
            Wt2_h + (size_t)l * 16384, Wt2_l + (size_t)l * 16384, mlp2_b + (size_t)l * HH,
            xout, pooled8, batch, NN);
        if (l < LL - 1)
            vn_update_k<<<BB, 128, 0, stream>>>(pooled8, gstart, vn_w0, vn_b0, vn_w1, vn_b1, vn, vnB);
        xin = xout;
    }
    fc_k<<<BB, 128, 0, stream>>>(pooled8, gstart, fc_W, fc_b, (float*)d_out);
}

// Round 10
// 581.354 us; speedup vs baseline: 1.1734x; 1.0131x over previous
//
#include <hip/hip_runtime.h>

#define NN 50000
#define EE 600000
#define HH 128
#define EDD 16
#define BB 256
#define LL 5
#define NN16 (NN * 16)
#define NSHADOW 8
#define GN 782    // (NN+63)/64  -- Cfrag block granularity
#define GN2 1563  // (NN+31)/32  -- layer_k grid

typedef float f32x4 __attribute__((ext_vector_type(4)));
typedef _Float16 f16x4 __attribute__((ext_vector_type(4)));
typedef _Float16 f16x8 __attribute__((ext_vector_type(8)));

// ---------------- all weight prep in one kernel ----------------
__global__ __launch_bounds__(256) void wprep_all_k(
    const float* __restrict__ W0, const float* __restrict__ W1, const float* __restrict__ W2,
    _Float16* __restrict__ H0, _Float16* __restrict__ L0,
    _Float16* __restrict__ H1, _Float16* __restrict__ L1,
    _Float16* __restrict__ H2, _Float16* __restrict__ L2,
    const float* __restrict__ eW, const float* __restrict__ eb, const float* __restrict__ nb,
    _Float16* __restrict__ BXh, _Float16* __restrict__ BXl)
{
    int idx = blockIdx.x * 256 + threadIdx.x;
    if (idx < 3 * 81920) {
        int seg = idx / 81920, r = idx - seg * 81920;
        const float* W = (seg == 0) ? W0 : (seg == 1) ? W1 : W2;
        _Float16* Wh = (seg == 0) ? H0 : (seg == 1) ? H1 : H2;
        _Float16* Wl = (seg == 0) ? L0 : (seg == 1) ? L1 : L2;
        int mat = r >> 14;
        int rr = r & 16383;
        int j = rr & 7, lane = (rr >> 3) & 63, ks = (rr >> 9) & 3, ntw = (rr >> 11) & 7;
        int lm = lane & 15, quad = lane >> 4;
        int n = (ntw >> 1) * 32 + (ntw & 1) * 16 + lm;
        int k = ks * 32 + quad * 8 + j;
        float w = W[(mat << 14) + (k << 7) + n];
        _Float16 h = (_Float16)w;
        Wh[r] = h;
        Wl[r] = (_Float16)(w - (float)h);
    } else {
        int i2 = idx - 3 * 81920;
        if (i2 >= 5 * 8192) return;
        int j = i2 & 7, lane = (i2 >> 3) & 63, ks = (i2 >> 9) & 1, ntw = (i2 >> 10) & 7, l = i2 >> 13;
        int lm = lane & 15, quad = lane >> 4;
        int n = (ntw >> 1) * 32 + (ntw & 1) * 16 + lm;
        int k = ks * 32 + quad * 8 + j;
        float v = 0.f;
        if (k < 16) v = eW[((size_t)l * 16 + k) * 128 + n];
        else if (k < 32) v = eW[((size_t)l * 16 + (k - 16)) * 128 + n];
        else if (k == 32) v = eb[l * 128 + n] + nb[l * 128 + n];
        _Float16 h = (_Float16)v;
        BXh[i2] = h;
        BXl[i2] = (_Float16)(v - (float)h);
    }
}

// ---------------- misc one-time: x->fp16, vn init, vnB zero, pooled8 zero ----------------
__global__ __launch_bounds__(256) void misc_k(const float* __restrict__ x, _Float16* __restrict__ X0,
    const float* __restrict__ vninit, float* __restrict__ vn, _Float16* __restrict__ vnB,
    float* __restrict__ pooled8)
{
    int i = blockIdx.x * 256 + threadIdx.x;
    if (i < NN * 32) {
        float4 v = ((const float4*)x)[i];
        f16x4 o;
        o[0] = (_Float16)v.x; o[1] = (_Float16)v.y; o[2] = (_Float16)v.z; o[3] = (_Float16)v.w;
        ((f16x4*)X0)[i] = o;
    } else {
        int k = i - NN * 32;
        if (k < NSHADOW * BB * HH) pooled8[k] = 0.f;
        if (k < BB * HH) { vn[k] = vninit[k & 127]; vnB[k] = (_Float16)0; }
    }
}

// ---------------- 4-wave GEMM helper for 32-row tile: acc[2][2] ----------------
__device__ __forceinline__ void mfma_stage32(
    const _Float16* __restrict__ As,
    const _Float16* __restrict__ Wh, const _Float16* __restrict__ Wl,
    int wn, int lm, int quad, int lane, f32x4 acc[2][2])
{
    f16x8 Bh[2][4], Bl[2][4];
#pragma unroll
    for (int nt = 0; nt < 2; ++nt)
#pragma unroll
        for (int ks = 0; ks < 4; ++ks) {
            int fi = ((((wn * 2 + nt) * 4) + ks) * 64 + lane) * 8;
            Bh[nt][ks] = *(const f16x8*)(Wh + fi);
            Bl[nt][ks] = *(const f16x8*)(Wl + fi);
        }
#pragma unroll
    for (int ks = 0; ks < 4; ++ks) {
        f16x8 a[2];
#pragma unroll
        for (int mt = 0; mt < 2; ++mt) {
            int off = (mt * 16 + lm) * 136 + ks * 32 + quad * 8;
            a[mt] = *(const f16x8*)(As + off);
        }
#pragma unroll
        for (int mt = 0; mt < 2; ++mt)
#pragma unroll
            for (int nt = 0; nt < 2; ++nt) {
                acc[mt][nt] = __builtin_amdgcn_mfma_f32_16x16x32_f16(a[mt], Bh[nt][ks], acc[mt][nt], 0, 0, 0);
                acc[mt][nt] = __builtin_amdgcn_mfma_f32_16x16x32_f16(a[mt], Bl[nt][ks], acc[mt][nt], 0, 0, 0);
            }
    }
}

// ---------------- fused layer kernel: 32-row tile, 256 threads, 4 waves (r4 MFMA pattern) ----------------
__global__ __launch_bounds__(256) void layer_k(
    const _Float16* __restrict__ Xin,
    const _Float16* __restrict__ Afix,
    const _Float16* __restrict__ Cfrag, const _Float16* __restrict__ vnB, int usevn,
    const int* __restrict__ rowstart, const int2* __restrict__ csr,
    const _Float16* __restrict__ WNh, const _Float16* __restrict__ WNl,
    const _Float16* __restrict__ BXh, const _Float16* __restrict__ BXl,
    const _Float16* __restrict__ W1h, const _Float16* __restrict__ W1l, const float* __restrict__ b1,
    const _Float16* __restrict__ W2h, const _Float16* __restrict__ W2l, const float* __restrict__ b2,
    _Float16* __restrict__ Xout, float* __restrict__ pooled8,
    const int* __restrict__ batch, int M)
{
    __shared__ __align__(16) _Float16 bufA[32 * 136];
    __shared__ __align__(16) _Float16 bufB[32 * 136];   // first 32*72 doubles as Afix stage
    const int tid = threadIdx.x, brow = blockIdx.x * 32;

    // stage Afix [32 x 64] fp16 at stride 72 into bufB
    {
        const int r = tid >> 3, cg = tid & 7;
        const int grow = brow + r;
        _Float16* p = bufB + r * 72 + cg * 8;
        if (grow < M) {
            *(f16x8*)p = *(const f16x8*)(Afix + (size_t)grow * 64 + cg * 8);
        } else {
            *(f16x8*)p = (f16x8)(_Float16)0;
        }
    }

    // gather phase: 16 groups x 2 rows each (r4 inner loop)
    {
        const int gid = tid >> 4, li = tid & 15;
        const f16x8* X8 = (const f16x8*)Xin;
#pragma unroll
        for (int j = 0; j < 2; ++j) {
            int rnode = gid * 2 + j;
            int node = brow + rnode;
            f16x8 o = (f16x8)(_Float16)0;
            if (node < M) {
                int s = rowstart[node], e = rowstart[node + 1];
                float ax[8];
#pragma unroll
                for (int k = 0; k < 8; ++k) ax[k] = 0.f;
                int p = s;
                for (; p + 4 <= e; p += 4) {
                    int s0 = csr[p].x, s1 = csr[p + 1].x, s2 = csr[p + 2].x, s3 = csr[p + 3].x;
                    f16x8 x0 = X8[(size_t)s0 * 16 + li];
                    f16x8 x1 = X8[(size_t)s1 * 16 + li];
                    f16x8 x2 = X8[(size_t)s2 * 16 + li];
                    f16x8 x3 = X8[(size_t)s3 * 16 + li];
#pragma unroll
                    for (int k = 0; k < 8; ++k)
                        ax[k] += ((float)x0[k] + (float)x1[k]) + ((float)x2[k] + (float)x3[k]);
                }
                for (; p < e; ++p) {
                    f16x8 x0 = X8[(size_t)csr[p].x * 16 + li];
#pragma unroll
                    for (int k = 0; k < 8; ++k) ax[k] += (float)x0[k];
                }
#pragma unroll
                for (int k = 0; k < 8; ++k) o[k] = (_Float16)ax[k];
            }
            *(f16x8*)(bufA + rnode * 136 + li * 8) = o;
        }
    }
    __syncthreads();

    const int lane = tid & 63, wn = tid >> 6, lm = lane & 15, quad = lane >> 4;
    const int colb = wn * 32 + lm;

    f32x4 acc[2][2];
#pragma unroll
    for (int mt = 0; mt < 2; ++mt) { acc[mt][0] = (f32x4)(0.f); acc[mt][1] = (f32x4)(0.f); }

    // K=64: [aggE_hi|aggE_lo|deg] @ [eW;eW;eb+nb]
#pragma unroll
    for (int ksf = 0; ksf < 2; ++ksf) {
        f16x8 Bh[2], Bl[2];
#pragma unroll
        for (int nt = 0; nt < 2; ++nt) {
            int fi = (((wn * 2 + nt) * 2 + ksf) * 64 + lane) * 8;
            Bh[nt] = *(const f16x8*)(BXh + fi);
            Bl[nt] = *(const f16x8*)(BXl + fi);
        }
#pragma unroll
        for (int mt = 0; mt < 2; ++mt) {
            f16x8 a = *(const f16x8*)(bufB + (mt * 16 + lm) * 72 + ksf * 32 + quad * 8);
#pragma unroll
            for (int nt = 0; nt < 2; ++nt) {
                acc[mt][nt] = __builtin_amdgcn_mfma_f32_16x16x32_f16(a, Bh[nt], acc[mt][nt], 0, 0, 0);
                acc[mt][nt] = __builtin_amdgcn_mfma_f32_16x16x32_f16(a, Bl[nt], acc[mt][nt], 0, 0, 0);
            }
        }
    }

    // K=256: C @ vn (32-row block b reads half of 64-row Cfrag block b>>1)
    if (usevn) {
        const _Float16* Cb = Cfrag + (size_t)(blockIdx.x >> 1) * 16384;
        const int mtoff = (blockIdx.x & 1) * 2;
#pragma unroll
        for (int ks = 0; ks < 8; ++ks) {
            f16x8 bv[2];
#pragma unroll
            for (int nt = 0; nt < 2; ++nt)
                bv[nt] = *(const f16x8*)(vnB + (((ks * 8 + (wn * 2 + nt)) * 64 + lane) * 8));
#pragma unroll
            for (int mt = 0; mt < 2; ++mt) {
                f16x8 av = *(const f16x8*)(Cb + ((((mtoff + mt) * 8 + ks) * 64 + lane) * 8));
                acc[mt][0] = __builtin_amdgcn_mfma_f32_16x16x32_f16(av, bv[0], acc[mt][0], 0, 0, 0);
                acc[mt][1] = __builtin_amdgcn_mfma_f32_16x16x32_f16(av, bv[1], acc[mt][1], 0, 0, 0);
            }
        }
    }

    // K=128: AggX @ nW
    mfma_stage32(bufA, WNh, WNl, wn, lm, quad, lane, acc);
    __syncthreads();

    // epilogue 1 (no relu; bias terms already inside GEMM): agg -> bufA
#pragma unroll
    for (int mt = 0; mt < 2; ++mt) {
#pragma unroll
        for (int r = 0; r < 4; ++r) {
            int trow = mt * 16 + quad * 4 + r;
            bufA[trow * 136 + colb]      = (_Float16)acc[mt][0][r];
            bufA[trow * 136 + colb + 16] = (_Float16)acc[mt][1][r];
        }
    }
    __syncthreads();

#pragma unroll
    for (int mt = 0; mt < 2; ++mt) { acc[mt][0] = (f32x4)(0.f); acc[mt][1] = (f32x4)(0.f); }
    mfma_stage32(bufA, W1h, W1l, wn, lm, quad, lane, acc);
    {
        const float c0 = b1[colb], c1 = b1[colb + 16];
#pragma unroll
        for (int mt = 0; mt < 2; ++mt) {
#pragma unroll
            for (int r = 0; r < 4; ++r) {
                int trow = mt * 16 + quad * 4 + r;
                bufB[trow * 136 + colb]      = (_Float16)fmaxf(acc[mt][0][r] + c0, 0.f);
                bufB[trow * 136 + colb + 16] = (_Float16)fmaxf(acc[mt][1][r] + c1, 0.f);
            }
        }
    }
    __syncthreads();

#pragma unroll
    for (int mt = 0; mt < 2; ++mt) { acc[mt][0] = (f32x4)(0.f); acc[mt][1] = (f32x4)(0.f); }
    mfma_stage32(bufB, W2h, W2l, wn, lm, quad, lane, acc);
    {
        const float d0 = b2[colb], d1 = b2[colb + 16];
#pragma unroll
        for (int mt = 0; mt < 2; ++mt) {
#pragma unroll
            for (int r = 0; r < 4; ++r) {
                int trow = mt * 16 + quad * 4 + r;
                bufA[trow * 136 + colb]      = (_Float16)fmaxf(acc[mt][0][r] + d0, 0.f);
                bufA[trow * 136 + colb + 16] = (_Float16)fmaxf(acc[mt][1][r] + d1, 0.f);
            }
        }
    }
    __syncthreads();

    // store (256 threads: 32 rows x 8 col-groups of 16 halfs)
    {
        const int r = tid >> 3, cg = tid & 7;
        const int grow = brow + r;
        if (grow < M) {
            const f16x8* src = (const f16x8*)(bufA + r * 136 + cg * 16);
            f16x8* dst = (f16x8*)(Xout + (size_t)grow * 128 + cg * 16);
            dst[0] = src[0];
            dst[1] = src[1];
        }
    }

    // pooled partial sums into shadow copy (blockIdx&7): 2 segments x 16 rows
    {
        float* pooled = pooled8 + (size_t)(blockIdx.x & (NSHADOW - 1)) * (BB * HH);
        const int c = tid & 127, half = tid >> 7;
        const int row0 = half * 16;
        float sum = 0.f;
        int curg = -1;
        for (int r2 = 0; r2 < 16; ++r2) {
            int grow = brow + row0 + r2;
            if (grow >= M) break;
            int g = batch[grow];
            if (g != curg) {
                if (curg >= 0) atomicAdd(&pooled[curg * 128 + c], sum);
                curg = g; sum = 0.f;
            }
            sum += (float)bufA[(row0 + r2) * 136 + c];
        }
        if (curg >= 0) atomicAdd(&pooled[curg * 128 + c], sum);
    }
}

// ---------------- aggE + Afix merged: per-node eattr sum -> [hi|lo|deg|0] fp16 ----------------
__global__ __launch_bounds__(256) void aggfix_k(
    const float* __restrict__ eattr, const int* __restrict__ rowstart,
    const int2* __restrict__ csr, _Float16* __restrict__ Afix, int n)
{
    const int lane = threadIdx.x & 15;
    const int node = blockIdx.x * 16 + (threadIdx.x >> 4);
    if (node >= n) return;
    const int s = rowstart[node], e = rowstart[node + 1];
    float acc = 0.f;
    for (int p = s; p < e; ++p)
        acc += eattr[(size_t)csr[p].y * 16 + lane];
    _Float16 hi = (_Float16)acc;
    _Float16 lo = (_Float16)(acc - (float)hi);
    _Float16* A = Afix + (size_t)node * 64;
    A[lane] = hi;
    A[16 + lane] = lo;
    A[32 + lane] = (lane == 0) ? (_Float16)(float)(e - s) : (_Float16)0;
    A[48 + lane] = (_Float16)0;
}

// ---------------- histogram (deg) + packed u16 Cfrag counts via u32 atomics ----------------
__global__ void histboth_k(const int* __restrict__ dstv, const int* __restrict__ srcv,
                           const int* __restrict__ batch,
                           int* __restrict__ degp, unsigned int* __restrict__ Cpack)
{
    int i = blockIdx.x * 256 + threadIdx.x;
    if (i >= EE) return;
    int d = dstv[i];
    atomicAdd(&degp[(blockIdx.x & 3) * NN16 + (d << 4)], 1);
    int g = batch[srcv[i]];
    int blk = d >> 6, rib = d & 63, mt = rib >> 4, lm = rib & 15;
    int ks = g >> 5, quad = (g >> 3) & 3, j = g & 7;
    size_t e = (size_t)blk * 16384 + (size_t)(((mt * 8 + ks) * 64) + quad * 16 + lm) * 8 + j;
    atomicAdd(&Cpack[e >> 1], 1u << ((e & 1) * 16));
}

// ---------------- in-place convert packed u16 counts -> fp16 ----------------
__global__ __launch_bounds__(256) void ccvt_k(unsigned int* __restrict__ Cpack)
{
    int i = blockIdx.x * 256 + threadIdx.x;
    if (i >= GN * 16384 / 2) return;
    unsigned int v = Cpack[i];
    _Float16 lo = (_Float16)(float)(v & 0xffffu);
    _Float16 hi = (_Float16)(float)(v >> 16);
    unsigned short lu = __builtin_bit_cast(unsigned short, lo);
    unsigned short hu = __builtin_bit_cast(unsigned short, hi);
    Cpack[i] = (unsigned int)lu | ((unsigned int)hu << 16);
}

// ---------------- VN update (writes frag-ordered vnB) ----------------
__global__ __launch_bounds__(128) void vn_update_k(
    float* __restrict__ pooled8, const int* __restrict__ gstart,
    const float* __restrict__ W0, const float* __restrict__ b0,
    const float* __restrict__ W1, const float* __restrict__ b1,
    float* __restrict__ vn, _Float16* __restrict__ vnB)
{
    __shared__ float p[128], q[128];
    const int g = blockIdx.x, t = threadIdx.x;
    float cnt = (float)(gstart[g + 1] - gstart[g]);
    if (cnt < 1.f) cnt = 1.f;
    float sum = 0.f;
#pragma unroll
    for (int s = 0; s < NSHADOW; ++s) {
        float* slot = pooled8 + (size_t)s * (BB * HH) + g * 128 + t;
        sum += *slot;
        *slot = 0.f;
    }
    p[t] = sum / cnt;
    __syncthreads();
    float a0 = b0[t];
    for (int k = 0; k < 128; ++k) a0 = fmaf(p[k], W0[k * 128 + t], a0);
    q[t] = fmaxf(a0, 0.f);
    __syncthreads();
    float a1 = b1[t];
    for (int k = 0; k < 128; ++k) a1 = fmaf(q[k], W1[k * 128 + t], a1);
    float nv = vn[g * 128 + t] + fmaxf(a1, 0.f);
    vn[g * 128 + t] = nv;
    {
        int ks = g >> 5, quad = (g >> 3) & 3, j = g & 7;
        int tt = ((t >> 5) << 1) | ((t >> 4) & 1);
        int lanev = quad * 16 + (t & 15);
        vnB[((ks * 8 + tt) * 64 + lanev) * 8 + j] = (_Float16)nv;
    }
}

// ---------------- final classifier ----------------
__global__ __launch_bounds__(128) void fc_k(
    const float* __restrict__ pooled8, const int* __restrict__ gstart,
    const float* __restrict__ W, const float* __restrict__ b,
    float* __restrict__ out)
{
    __shared__ float p[128];
    const int g = blockIdx.x, t = threadIdx.x;
    float cnt = (float)(gstart[g + 1] - gstart[g]);
    if (cnt < 1.f) cnt = 1.f;
    float sum = 0.f;
#pragma unroll
    for (int s = 0; s < NSHADOW; ++s)
        sum += pooled8[(size_t)s * (BB * HH) + g * 128 + t];
    p[t] = sum / cnt;
    __syncthreads();
    float acc = b[t];
    for (int k = 0; k < 128; ++k) acc = fmaf(p[k], W[k * 128 + t], acc);
    out[g * 128 + t] = acc;
}

// ---------------- CSR build ----------------
__global__ void scan_deg_k(const int* __restrict__ degp, int n, int* __restrict__ out, int* __restrict__ bsum)
{
    __shared__ int s[256];
    int gid = blockIdx.x * 256 + threadIdx.x;
    int v = 0;
    if (gid < n) {
        int o = gid << 4;
        v = degp[o] + degp[NN16 + o] + degp[2 * NN16 + o] + degp[3 * NN16 + o];
    }
    s[threadIdx.x] = v;
    __syncthreads();
    for (int off = 1; off < 256; off <<= 1) {
        int t = (threadIdx.x >= off) ? s[threadIdx.x - off] : 0;
        __syncthreads();
        s[threadIdx.x] += t;
        __syncthreads();
    }
    int incl = s[threadIdx.x];
    if (gid < n) out[gid] = incl - v;
    if (bsum != nullptr && threadIdx.x == 255) bsum[blockIdx.x] = incl;
}

__global__ void scan_k(const int* __restrict__ in, int n, int* __restrict__ out,
                       const int* __restrict__ batch, int* __restrict__ gstart)
{
    __shared__ int s[256];
    int v = (threadIdx.x < n) ? in[threadIdx.x] : 0;
    s[threadIdx.x] = v;
    __syncthreads();
    for (int off = 1; off < 256; off <<= 1) {
        int t = (threadIdx.x >= off) ? s[threadIdx.x - off] : 0;
        __syncthreads();
        s[threadIdx.x] += t;
        __syncthreads();
    }
    if (threadIdx.x < n) out[threadIdx.x] = s[threadIdx.x] - v;
    {
        int b = threadIdx.x;
        int lo = 0, hi = NN;
        while (lo < hi) {
            int mid = (lo + hi) >> 1;
            if (batch[mid] < b) lo = mid + 1; else hi = mid;
        }
        gstart[b] = lo;
        if (threadIdx.x == 0) gstart[BB] = NN;
    }
}

__global__ void addoff_k(int* __restrict__ data, const int* __restrict__ boff,
                         int* __restrict__ cursorp, int n, int total)
{
    int i = blockIdx.x * 256 + threadIdx.x;
    if (i < n) {
        int v = data[i] + boff[blockIdx.x];
        data[i] = v;
        cursorp[i << 4] = v;
    }
    if (i == 0) data[n] = total;
}

__global__ void fill_k(const int* __restrict__ dst, const int* __restrict__ src, int n,
                       int* __restrict__ cursorp, int2* __restrict__ csr)
{
    int e = blockIdx.x * 256 + threadIdx.x;
    if (e < n) {
        int slot = atomicAdd(&cursorp[dst[e] << 4], 1);
        int2 pr; pr.x = src[e]; pr.y = e;
        csr[slot] = pr;
    }
}

// ---------------- Launch ----------------
extern "C" void kernel_launch(void* const* d_in, const int* in_sizes, int n_in,
                              void* d_out, int out_size, void* d_ws, size_t ws_size,
                              hipStream_t stream)
{
    (void)in_sizes; (void)n_in; (void)out_size; (void)ws_size;
    const float* x       = (const float*)d_in[0];
    const float* eattr   = (const float*)d_in[1];
    const float* node_W  = (const float*)d_in[2];
    const float* node_b  = (const float*)d_in[3];
    const float* edge_W  = (const float*)d_in[4];
    const float* edge_b  = (const float*)d_in[5];
    const float* mlp1_W  = (const float*)d_in[6];
    const float* mlp1_b  = (const float*)d_in[7];
    const float* mlp2_W  = (const float*)d_in[8];
    const float* mlp2_b  = (const float*)d_in[9];
    const float* vn_w0   = (const float*)d_in[10];
    const float* vn_b0   = (const float*)d_in[11];
    const float* vn_w1   = (const float*)d_in[12];
    const float* vn_b1   = (const float*)d_in[13];
    const float* fc_W    = (const float*)d_in[14];
    const float* fc_b    = (const float*)d_in[15];
    const float* vn_init = (const float*)d_in[16];
    const int*   eidx    = (const int*)d_in[17];
    const int*   batch   = (const int*)d_in[18];
    const int* srcv = eidx;
    const int* dstv = eidx + EE;

    char* wp = (char*)d_ws;
    auto alloc = [&](size_t bytes) -> void* {
        void* p = (void*)wp;
        wp += (bytes + 255) & ~(size_t)255;
        return p;
    };
    // zero-init region: degp | Cfrag contiguous (one memset)
    int* degp       = (int*)alloc((size_t)4 * NN16 * 4);             // 12.8 MB
    _Float16* Cfrag = (_Float16*)alloc((size_t)GN * 16384 * 2);      // 25.6 MB
    const size_t zero_bytes = (size_t)4 * NN16 * 4 + (size_t)GN * 16384 * 2;

    _Float16* X0   = (_Float16*)alloc((size_t)NN * HH * 2);
    _Float16* X1   = (_Float16*)alloc((size_t)NN * HH * 2);
    _Float16* X2   = (_Float16*)alloc((size_t)NN * HH * 2);
    _Float16* Afix = (_Float16*)alloc((size_t)NN * 64 * 2);
    float* vn      = (float*)alloc((size_t)BB * HH * 4);
    _Float16* vnB  = (_Float16*)alloc((size_t)BB * HH * 2);
    float* pooled8 = (float*)alloc((size_t)NSHADOW * BB * HH * 4);
    int* rowstart  = (int*)alloc((size_t)(NN + 1) * 4);
    int* cursorp   = (int*)alloc((size_t)NN16 * 4);
    int2* csr      = (int2*)alloc((size_t)EE * 8);
    int* bsum      = (int*)alloc(256 * 4);
    int* boff      = (int*)alloc(256 * 4);
    int* gstart    = (int*)alloc((size_t)(BB + 1) * 4);
    _Float16* WtN_h = (_Float16*)alloc((size_t)5 * 16384 * 2);
    _Float16* WtN_l = (_Float16*)alloc((size_t)5 * 16384 * 2);
    _Float16* Wt1_h = (_Float16*)alloc((size_t)5 * 16384 * 2);
    _Float16* Wt1_l = (_Float16*)alloc((size_t)5 * 16384 * 2);
    _Float16* Wt2_h = (_Float16*)alloc((size_t)5 * 16384 * 2);
    _Float16* Wt2_l = (_Float16*)alloc((size_t)5 * 16384 * 2);
    _Float16* BXh   = (_Float16*)alloc((size_t)5 * 8192 * 2);
    _Float16* BXl   = (_Float16*)alloc((size_t)5 * 8192 * 2);

    (void)hipMemsetAsync(degp, 0, zero_bytes, stream);

    histboth_k<<<(EE + 255) / 256, 256, 0, stream>>>(dstv, srcv, batch, degp, (unsigned int*)Cfrag);

    const int NB1 = (NN + 255) / 256;
    scan_deg_k<<<NB1, 256, 0, stream>>>(degp, NN, rowstart, bsum);
    scan_k<<<1, 256, 0, stream>>>(bsum, NB1, boff, batch, gstart);
    addoff_k<<<NB1, 256, 0, stream>>>(rowstart, boff, cursorp, NN, EE);
    fill_k<<<(EE + 255) / 256, 256, 0, stream>>>(dstv, srcv, EE, cursorp, csr);
    aggfix_k<<<(NN + 15) / 16, 256, 0, stream>>>(eattr, rowstart, csr, Afix, NN);
    ccvt_k<<<(GN * 16384 / 2 + 255) / 256, 256, 0, stream>>>((unsigned int*)Cfrag);

    misc_k<<<(NN * 32 + NSHADOW * BB * HH) / 256, 256, 0, stream>>>(x, X0, vn_init, vn, vnB, pooled8);
    wprep_all_k<<<(3 * 81920 + 5 * 8192) / 256, 256, 0, stream>>>(
        node_W, mlp1_W, mlp2_W, WtN_h, WtN_l, Wt1_h, Wt1_l, Wt2_h, Wt2_l,
        edge_W, edge_b, node_b, BXh, BXl);

    const _Float16* xin = X0;
    for (int l = 0; l < LL; ++l) {
        _Float16* xout = (l & 1) ? X2 : X1;
        layer_k<<<GN2, 256, 0, stream>>>(xin, Afix, Cfrag, vnB, (l > 0) ? 1 : 0,
            rowstart, csr,
            WtN_h + (size_t)l * 16384, WtN_l + (size_t)l * 16384,
            BXh + (size_t)l * 8192, BXl + (size_t)l * 8192,
            Wt1_h + (size_t)l * 16384, Wt1_l + (size_t)l * 16384, mlp1_b + (size_t)l * HH,
            Wt2_h + (size_t)l * 16384, Wt2_l + (size_t)l * 16384, mlp2_b + (size_t)l * HH,
            xout, pooled8, batch, NN);
        if (l < LL - 1)
            vn_update_k<<<BB, 128, 0, stream>>>(pooled8, gstart, vn_w0, vn_b0, vn_w1, vn_b1, vn, vnB);
        xin = xout;
    }
    fc_k<<<BB, 128, 0, stream>>>(pooled8, gstart, fc_W, fc_b, (float*)d_out);
}